// Round 15
// baseline (877.060 us; speedup 1.0000x reference)
//
#include <hip/hip_runtime.h>
#include <hip/hip_bf16.h>

#define N_NODES 50000
#define N_EDGES 640000
#define C_DIM 128
#define B_DIM 64
#define L_DIM 32
#define D_DIM 256
#define S_DIM 128
#define R_DIM 8
#define K_CONV 4
#define NPW 4         // nodes per gather wave
#define NB 64         // nodes per fused block (4 MFMA tiles)
#define MAX_CHUNK 50048
#define SCAN_BLK 49   // ceil(50000/1024)

typedef unsigned short u16;
typedef __attribute__((ext_vector_type(8))) short bf16x8;   // 8 bf16 = 4 VGPRs
typedef __attribute__((ext_vector_type(4))) float f32x4;

struct __align__(16) ERec { int s; float a0, a1; int pad; };

__device__ __forceinline__ float bu2f(u16 u){ return __uint_as_float(((unsigned)u) << 16); }
__device__ __forceinline__ u16 f2bu(float f){
  __hip_bfloat16 h = __float2bfloat16(f);
  return *reinterpret_cast<u16*>(&h);
}
__device__ __forceinline__ float sigmoidf_(float x){ return 1.f/(1.f + expf(-x)); }
__device__ __forceinline__ int clampi(int v, int lo, int hi){ return max(lo, min(v, hi)); }
__device__ __forceinline__ float ldf(const void* p, size_t i, int f){
  return f ? bu2f(((const u16*)p)[i]) : ((const float*)p)[i];
}
__device__ __forceinline__ void stf(void* p, size_t i, int f, float v){
  if (f) ((u16*)p)[i] = f2bu(v); else ((float*)p)[i] = v;
}
__device__ __forceinline__ f32x4 mfma16(bf16x8 a, bf16x8 b, f32x4 c){
  return __builtin_amdgcn_mfma_f32_16x16x32_bf16(a, b, c, 0, 0, 0);
}
__device__ __forceinline__ float wave_sum64(float v){
  #pragma unroll
  for (int off = 32; off; off >>= 1) v += __shfl_xor(v, off);
  return v;
}

// weight arena layout (element offsets); 27 segments in d_in[4..30] order
constexpr int K_SEG = 27;
constexpr int kCum[K_SEG+1] = {
  0, 2048, 3072, 134144, 135168, 184320, 233472, 233856, 234240, 299776,
  300800, 301056, 368640, 370688, 370944, 403712, 403968, 436736, 436864,
  436992, 584448, 584576, 584704, 584832, 601216, 601344, 601472, 601600 };
#define ARENA_TOTAL 601600

struct Ptrs { const void* p[K_SEG]; };

// ---------------- detection (64-lane parallel) ----------------

__global__ void detect_kernel(const unsigned* dp_bits, const unsigned* cand1,
                              const unsigned* cand2, int* flags){
  int lane = threadIdx.x & 63;
  unsigned idx = (unsigned)((lane * 9973u) % (unsigned)N_EDGES);
  int v1 = (cand1[idx] < (unsigned)N_NODES) ? 1 : 0;
  int v2 = (cand2[idx] < (unsigned)N_NODES) ? 1 : 0;
  unsigned long long m1 = __ballot(v1);
  unsigned long long m2 = __ballot(v2);
  if (lane == 0){
    flags[0] = (dp_bits[0] == 0x3F803F80u) ? 1 : 0;
    flags[1] = (__popcll(m1) > __popcll(m2)) ? 1 : 0;   // 1 => d_in[1] is edge_index
  }
}

// ---------------- fused weight-convert ----------------

__global__ __launch_bounds__(256) void cvt_all_kernel(Ptrs ptrs, float* arena,
                                                      const int* flags){
  int i = blockIdx.x*256 + threadIdx.x;
  if (i >= ARENA_TOTAL) return;
  int lo = 0, hi = K_SEG;
  #pragma unroll
  for (int it = 0; it < 5; it++){
    int mid = (lo + hi) >> 1;
    if (i >= kCum[mid]) lo = mid; else hi = mid;
  }
  int elem = i - kCum[lo];
  const void* sp = ptrs.p[lo];
  arena[i] = flags[0] ? bu2f(((const u16*)sp)[elem]) : ((const float*)sp)[elem];
}

// ---------------- weight transpose + bf16 hi/lo split for MFMA ----------------

__global__ __launch_bounds__(256) void wtrans_kernel(
    const float* __restrict__ WcF, const float* __restrict__ Wm1F,
    const float* __restrict__ Wm2F,
    u16* __restrict__ WcT_hi, u16* __restrict__ WcT_lo,
    u16* __restrict__ Wm1T_hi, u16* __restrict__ Wm1T_lo,
    u16* __restrict__ Wm2T_hi, u16* __restrict__ Wm2T_lo)
{
  int i = blockIdx.x*256 + threadIdx.x;
  if (i >= 8*C_DIM*C_DIM) return;
  int h = i >> 14, j = (i >> 7) & 127, k = i & 127;
  {
    float w = WcF[(h<<14) + (k<<7) + j];
    u16 hi = f2bu(w); u16 lo = f2bu(w - bu2f(hi));
    WcT_hi[i] = hi; WcT_lo[i] = lo;
  }
  {
    float w = Wm1F[((size_t)((h<<7) + k) << 7) + j];
    u16 hi = f2bu(w); u16 lo = f2bu(w - bu2f(hi));
    Wm1T_hi[i] = hi; Wm1T_lo[i] = lo;
  }
  if (i < C_DIM*C_DIM){
    int j2 = i >> 7, k2 = i & 127;
    float w = Wm2F[(k2<<7) + j2];
    u16 hi = f2bu(w); u16 lo = f2bu(w - bu2f(hi));
    Wm2T_hi[i] = hi; Wm2T_lo[i] = lo;
  }
}

// ---------------- counting sort of edges by dst ----------------

__global__ void hist_kernel(const int* __restrict__ eiA, const int* __restrict__ eiB,
                            const int* __restrict__ flags, int* __restrict__ hist){
  const int* dst = (flags[1] ? eiA : eiB) + N_EDGES;
  int e = blockIdx.x*256 + threadIdx.x;
  if (e >= N_EDGES) return;
  int d = clampi(dst[e], 0, N_NODES-1);
  atomicAdd(&hist[d], 1);
}

__global__ __launch_bounds__(1024) void scan1_kernel(const int* __restrict__ hist,
                                                     int* __restrict__ tmp,
                                                     int* __restrict__ bsums){
  __shared__ int buf[1024];
  int b = blockIdx.x, tid = threadIdx.x;
  int i = b*1024 + tid;
  int v = (i < N_NODES) ? hist[i] : 0;
  buf[tid] = v;
  __syncthreads();
  for (int off = 1; off < 1024; off <<= 1){
    int t = (tid >= off) ? buf[tid-off] : 0;
    __syncthreads();
    buf[tid] += t;
    __syncthreads();
  }
  if (i < N_NODES) tmp[i] = buf[tid];       // inclusive
  if (tid == 1023) bsums[b] = buf[1023];
}

__global__ void scan2_kernel(int* __restrict__ bsums, int* __restrict__ offsets){
  if (threadIdx.x == 0){
    int run = 0;
    for (int b = 0; b < SCAN_BLK; b++){ int v = bsums[b]; bsums[b] = run; run += v; }
    offsets[N_NODES] = run;
  }
}

__global__ __launch_bounds__(1024) void scan3_kernel(int* __restrict__ offsets,
                                                     int* __restrict__ hist,
                                                     const int* __restrict__ bsums){
  int b = blockIdx.x, tid = threadIdx.x;
  int i = b*1024 + tid;
  if (i >= N_NODES) return;
  int incl = offsets[i];
  int h = hist[i];
  int excl = incl - h + bsums[b];
  offsets[i] = excl;
  hist[i] = excl;       // cursor copy for perm_kernel
}

__global__ void perm_kernel(const void* __restrict__ in1, const void* __restrict__ in2,
                            const int* __restrict__ flags, int* __restrict__ cursor,
                            ERec* __restrict__ sortedRec){
  int e = blockIdx.x*256 + threadIdx.x;
  if (e >= N_EDGES) return;
  const int f1 = flags[1], f = flags[0];
  const int* ei  = (const int*)(f1 ? in1 : in2);
  const void* eav = f1 ? in2 : in1;
  int d = clampi(ei[N_EDGES + e], 0, N_NODES-1);
  int s = clampi(ei[e], 0, N_NODES-1);
  float a0, a1;
  if (f){ const u16* e16 = (const u16*)eav; a0 = bu2f(e16[2*e]); a1 = bu2f(e16[2*e+1]); }
  else  { const float* e32 = (const float*)eav; a0 = e32[2*e]; a1 = e32[2*e+1]; }
  int pos = atomicAdd(&cursor[d], 1);
  pos = clampi(pos, 0, N_EDGES-1);
  ERec r; r.s = s; r.a0 = a0; r.a1 = a1; r.pad = 0;
  sortedRec[pos] = r;
}

// ---------------- edge gather -> agg (bf16 hi/lo planes) ----------------
// Wave = (chalf, 4-node set). Weights stay in VGPRs across all 4 nodes; each
// wave owns its nodes' channel-half completely -> no LDS, no barriers.
// Edge record packed 16B (one dwordx4 per edge). agg: [nl][h][{hi,lo}][128].

__global__ __launch_bounds__(256, 8) void gather_kernel(
    const void* __restrict__ xv, const ERec* __restrict__ sortedRec,
    const int* __restrict__ offsets,
    const float* __restrict__ WeF, const float* __restrict__ beF,
    const int* __restrict__ flags, u16* __restrict__ aggBuf,
    int n0, int ncnt)
{
  int w = blockIdx.x*4 + (threadIdx.x >> 6);
  int nsets = (ncnt + NPW - 1) / NPW;
  if (w >= 2*nsets) return;
  int chalf = w & 1;
  int nset = w >> 1;
  int lane = threadIdx.x & 63;
  int c = lane + chalf*64;
  const int f = flags[0];
  const u16* x16 = (const u16*)xv; const float* x32 = (const float*)xv;

  float we0[8], we1[8], beh[8];
  #pragma unroll
  for (int h = 0; h < 8; h++){
    we0[h] = WeF[h*2*C_DIM + c];
    we1[h] = WeF[h*2*C_DIM + C_DIM + c];
    beh[h] = beF[h*C_DIM + c];
  }

  auto LD = [&](int q, float& xr, float2& er){
    ERec r = sortedRec[q];          // one 16B load
    er = make_float2(r.a0, r.a1);
    int idx = r.s*C_DIM + c;
    xr = f ? bu2f(x16[idx]) : x32[idx];
  };

  int nl_end = min(nset*NPW + NPW, ncnt);
  for (int nl = nset*NPW; nl < nl_end; nl++){
    int n = n0 + nl;
    int q0 = offsets[n];
    int cnt = offsets[n+1] - q0;

    float acc[8] = {0,0,0,0,0,0,0,0};
    float xA=0.f, xB=0.f, xC=0.f, xD=0.f;
    float2 eA=make_float2(0,0), eB=make_float2(0,0), eC=make_float2(0,0), eD=make_float2(0,0);
    if (cnt > 0) LD(q0+0, xA, eA);
    if (cnt > 1) LD(q0+1, xB, eB);
    if (cnt > 2) LD(q0+2, xC, eC);
    if (cnt > 3) LD(q0+3, xD, eD);

    for (int j = 0; j < cnt; j += 4){
      float ux0=xA, ux1=xB, ux2=xC, ux3=xD;
      float2 ue0=eA, ue1=eB, ue2=eC, ue3=eD;
      if (j+4 < cnt) LD(q0+j+4, xA, eA);
      if (j+5 < cnt) LD(q0+j+5, xB, eB);
      if (j+6 < cnt) LD(q0+j+6, xC, eC);
      if (j+7 < cnt) LD(q0+j+7, xD, eD);
      #pragma unroll
      for (int h = 0; h < 8; h++)
        acc[h] += fmaxf(fmaf(ue0.x, we0[h], fmaf(ue0.y, we1[h], ux0 + beh[h])), 0.f);
      if (j+1 < cnt){
        #pragma unroll
        for (int h = 0; h < 8; h++)
          acc[h] += fmaxf(fmaf(ue1.x, we0[h], fmaf(ue1.y, we1[h], ux1 + beh[h])), 0.f);
      }
      if (j+2 < cnt){
        #pragma unroll
        for (int h = 0; h < 8; h++)
          acc[h] += fmaxf(fmaf(ue2.x, we0[h], fmaf(ue2.y, we1[h], ux2 + beh[h])), 0.f);
      }
      if (j+3 < cnt){
        #pragma unroll
        for (int h = 0; h < 8; h++)
          acc[h] += fmaxf(fmaf(ue3.x, we0[h], fmaf(ue3.y, we1[h], ux3 + beh[h])), 0.f);
      }
    }

    int base = nl*2048 + c;
    #pragma unroll
    for (int h = 0; h < 8; h++){
      u16 hv = f2bu(acc[h]);
      u16 lv = f2bu(acc[h] - bu2f(hv));
      aggBuf[base + h*256]       = hv;
      aggBuf[base + h*256 + 128] = lv;
    }
  }
}

// ---------------- pooling ----------------

__global__ __launch_bounds__(128) void pool_kernel(
    const void* __restrict__ xv, const int* __restrict__ batch,
    float* __restrict__ xsum, int* __restrict__ counts, const int* __restrict__ flags)
{
  int c = threadIdx.x;
  int f = flags[0];
  int n0 = blockIdx.x * 32;
  int nend = min(n0 + 32, N_NODES);
  float acc = 0.f; int cnt = 0;
  int curb = clampi(batch[n0], 0, B_DIM-1);
  for (int n = n0; n < nend; n++){
    int b = clampi(batch[n], 0, B_DIM-1);
    if (b != curb){
      atomicAdd(&xsum[curb*C_DIM + c], acc);
      if (c == 0) atomicAdd(&counts[curb], cnt);
      acc = 0.f; cnt = 0; curb = b;
    }
    acc += ldf(xv, (size_t)n*C_DIM + c, f);
    cnt++;
  }
  atomicAdd(&xsum[curb*C_DIM + c], acc);
  if (c == 0) atomicAdd(&counts[curb], cnt);
}

// ---------------- GRU (Whh column register-cached) ----------------

__global__ __launch_bounds__(384, 1) void gru_kernel(
    const float* __restrict__ xsum, const int* __restrict__ counts,
    const float* __restrict__ Wih, const float* __restrict__ bih,
    const float* __restrict__ Whh, const float* __restrict__ bhh,
    float* __restrict__ tokens)
{
  int b = blockIdx.x, j = threadIdx.x;
  __shared__ float xm[C_DIM], h[C_DIM], gh[3*C_DIM], sgi[3*C_DIM];
  __shared__ float mxS;
  if (j == 0){
    int m = 1;
    for (int bb = 0; bb < B_DIM; bb++) m = max(m, counts[bb]);
    mxS = (float)m;
  }
  __syncthreads();
  if (j < C_DIM){ xm[j] = xsum[b*C_DIM + j] / mxS; h[j] = 0.f; }
  __syncthreads();

  {
    float a0=0.f, a1=0.f, a2=0.f, a3=0.f;
    for (int k = 0; k < C_DIM; k += 4){
      a0 = fmaf(xm[k],   Wih[(k  )*384 + j], a0);
      a1 = fmaf(xm[k+1], Wih[(k+1)*384 + j], a1);
      a2 = fmaf(xm[k+2], Wih[(k+2)*384 + j], a2);
      a3 = fmaf(xm[k+3], Wih[(k+3)*384 + j], a3);
    }
    sgi[j] = bih[j] + ((a0 + a1) + (a2 + a3));
  }

  float w[C_DIM];
  #pragma unroll
  for (int k = 0; k < C_DIM; k++) w[k] = Whh[k*384 + j];
  float bh = bhh[j];
  __syncthreads();

  float g_ir = 0.f, g_iz = 0.f, g_in = 0.f;
  if (j < C_DIM){ g_ir = sgi[j]; g_iz = sgi[C_DIM + j]; g_in = sgi[2*C_DIM + j]; }

  for (int t = 0; t < L_DIM; t++){
    float a0=0.f, a1=0.f, a2=0.f, a3=0.f;
    #pragma unroll
    for (int k = 0; k < C_DIM; k += 4){
      a0 = fmaf(h[k],   w[k],   a0);
      a1 = fmaf(h[k+1], w[k+1], a1);
      a2 = fmaf(h[k+2], w[k+2], a2);
      a3 = fmaf(h[k+3], w[k+3], a3);
    }
    gh[j] = bh + ((a0 + a1) + (a2 + a3));
    __syncthreads();
    if (j < C_DIM){
      float r  = sigmoidf_(g_ir + gh[j]);
      float z  = sigmoidf_(g_iz + gh[C_DIM + j]);
      float nn = tanhf(g_in + r*gh[2*C_DIM + j]);
      float hn = (1.f - z)*nn + z*h[j];
      h[j] = hn;
      tokens[((size_t)b*L_DIM + t)*C_DIM + j] = hn;
    }
    __syncthreads();
  }
}

// ---------------- token projection (Win) ----------------

__global__ __launch_bounds__(256) void token_proj_kernel(
    const float* __restrict__ tokens, const float* __restrict__ Win,
    float* __restrict__ x_in, float* __restrict__ z_last)
{
  int row = blockIdx.x;
  int d = threadIdx.x;
  __shared__ float tok[C_DIM];
  if (d < C_DIM) tok[d] = tokens[(size_t)row*C_DIM + d];
  __syncthreads();
  float acc = 0.f;
  for (int k = 0; k < C_DIM; k++) acc = fmaf(tok[k], Win[k*512 + d], acc);
  x_in[(size_t)row*D_DIM + d] = acc;
  if ((row & (L_DIM-1)) == L_DIM-1){
    float acc2 = 0.f;
    for (int k = 0; k < C_DIM; k++) acc2 = fmaf(tok[k], Win[k*512 + D_DIM + d], acc2);
    z_last[(row >> 5)*D_DIM + d] = acc2;
  }
}

// ---------------- xproj ----------------

__global__ __launch_bounds__(256) void xproj_kernel(
    const float* __restrict__ x_in, const float* __restrict__ cw,
    const float* __restrict__ cb, const float* __restrict__ Wx,
    const float* __restrict__ Wdt, const float* __restrict__ bdt,
    float* __restrict__ dt, float* __restrict__ Bp, float* __restrict__ Cp,
    float* __restrict__ x_c)
{
  int row = blockIdx.x; int tid = threadIdx.x;
  int t = row & (L_DIM-1);
  __shared__ float xr[D_DIM];
  __shared__ float dtr[R_DIM];
  float acc0 = cb[tid];
  #pragma unroll
  for (int k = 0; k < K_CONV; k++){
    int tt = t + k - (K_CONV-1);
    if (tt >= 0) acc0 = fmaf(cw[tid*K_CONV + k], x_in[(size_t)(row + tt - t)*D_DIM + tid], acc0);
  }
  float xcv = acc0 * sigmoidf_(acc0);
  x_c[(size_t)row*D_DIM + tid] = xcv;
  xr[tid] = xcv;
  __syncthreads();
  float acc = 0.f;
  #pragma unroll 4
  for (int k = 0; k < D_DIM; k++) acc = fmaf(xr[k], Wx[k*264 + tid], acc);
  if (tid < R_DIM)              dtr[tid] = acc;
  else if (tid < R_DIM+S_DIM)   Bp[(size_t)row*S_DIM + tid - R_DIM] = acc;
  else                          Cp[(size_t)row*S_DIM + tid - (R_DIM+S_DIM)] = acc;
  if (tid < 264 - D_DIM){
    float acc2 = 0.f;
    #pragma unroll 4
    for (int k = 0; k < D_DIM; k++) acc2 = fmaf(xr[k], Wx[k*264 + D_DIM + tid], acc2);
    Cp[(size_t)row*S_DIM + (D_DIM - (R_DIM+S_DIM)) + tid] = acc2;
  }
  __syncthreads();
  float a = bdt[tid];
  #pragma unroll
  for (int r = 0; r < R_DIM; r++) a = fmaf(dtr[r], Wdt[r*D_DIM + tid], a);
  dt[(size_t)row*D_DIM + tid] = (a > 20.f) ? a : log1pf(expf(a));
}

// ---------------- SSM scan ----------------

__global__ __launch_bounds__(256) void ssm_kernel(
    const float* __restrict__ dt, const float* __restrict__ Bp,
    const float* __restrict__ Cp, const float* __restrict__ x_c,
    const float* __restrict__ A_log, const float* __restrict__ Dp_,
    const float* __restrict__ z_last, float* __restrict__ y_last)
{
  int wid = (blockIdx.x*256 + threadIdx.x) >> 6;
  int lane = threadIdx.x & 63;
  int b = wid >> 8, d = wid & (D_DIM-1);
  int s0 = lane*2;
  float A0 = -expf(A_log[d*S_DIM + s0]);
  float A1 = -expf(A_log[d*S_DIM + s0 + 1]);
  float h0 = 0.f, h1 = 0.f;
  for (int t = 0; t < L_DIM; t++){
    int row = b*L_DIM + t;
    float dtv = dt[(size_t)row*D_DIM + d];
    float xv  = x_c[(size_t)row*D_DIM + d];
    float bx = dtv * xv;
    float2 Bv = ((const float2*)(Bp + (size_t)row*S_DIM))[lane];
    h0 = fmaf(expf(dtv*A0), h0, bx*Bv.x);
    h1 = fmaf(expf(dtv*A1), h1, bx*Bv.y);
  }
  int row = b*L_DIM + (L_DIM-1);
  float2 Cv = ((const float2*)(Cp + (size_t)row*S_DIM))[lane];
  float y = h0*Cv.x + h1*Cv.y;
  #pragma unroll
  for (int off = 32; off; off >>= 1) y += __shfl_down(y, off);
  if (lane == 0){
    float xc = x_c[(size_t)row*D_DIM + d];
    float yv = y + Dp_[d]*xc;
    float z  = z_last[b*D_DIM + d];
    yv *= z * sigmoidf_(z);
    y_last[b*D_DIM + d] = yv;
  }
}

// ---------------- proj = ln(y_last @ Wout) @ Wm1[8C:] ----------------

__device__ __forceinline__ float block_sum_128(float v, float* red){
  int c = threadIdx.x;
  red[c] = v; __syncthreads();
  if (c < 64) red[c] += red[c+64];
  __syncthreads();
  if (c < 64){
    float r = red[c];
    #pragma unroll
    for (int off = 32; off; off >>= 1) r += __shfl_down(r, off);
    if (c == 0) red[0] = r;
  }
  __syncthreads();
  float out = red[0];
  __syncthreads();
  return out;
}

__global__ __launch_bounds__(128) void xm_kernel(
    const float* __restrict__ y_last, const float* __restrict__ Wout,
    const float* __restrict__ g_m, const float* __restrict__ b_m,
    const float* __restrict__ Wm1x, float* __restrict__ proj)
{
  int b = blockIdx.x, c = threadIdx.x;
  __shared__ float yr[D_DIM];
  __shared__ float red[C_DIM];
  __shared__ float xmr[C_DIM];
  yr[c]        = y_last[b*D_DIM + c];
  yr[C_DIM+c]  = y_last[b*D_DIM + C_DIM + c];
  __syncthreads();
  float acc = 0.f;
  for (int k = 0; k < D_DIM; k++) acc = fmaf(yr[k], Wout[k*C_DIM + c], acc);
  float mean = block_sum_128(acc, red) * (1.f/C_DIM);
  float dv = acc - mean;
  float var = block_sum_128(dv*dv, red) * (1.f/C_DIM);
  float mo = dv*rsqrtf(var + 1e-5f)*g_m[c] + b_m[c];
  xmr[c] = mo;
  __syncthreads();
  float p = 0.f;
  for (int k = 0; k < C_DIM; k++) p = fmaf(xmr[k], Wm1x[k*C_DIM + c], p);
  proj[b*C_DIM + c] = p;
}

// ---------------- fused_kernel: 64 nodes/block, 256 threads, 3 blocks/CU ----------------
// agg A-fragments read DIRECTLY from global (L2-resident; all 4 waves share
// addresses -> L1 amortized). No staging phase, no agg LDS. LN phases tiled
// 16 rows through an 8KB pS scratch. LDS = Y 32KB + pS 8KB = 40KB -> 3/CU.

__global__ __launch_bounds__(256, 3) void fused_kernel(
    const void* __restrict__ xv, const u16* __restrict__ aggBuf, int n0, int ncnt,
    const u16* __restrict__ WcT_hi, const u16* __restrict__ WcT_lo,
    const float* __restrict__ bcF,
    const u16* __restrict__ Wm1T_hi, const u16* __restrict__ Wm1T_lo,
    const float* __restrict__ bm1F, const float* __restrict__ proj,
    const int* __restrict__ batch,
    const float* __restrict__ ghF, const float* __restrict__ bhF,
    const u16* __restrict__ Wm2T_hi, const u16* __restrict__ Wm2T_lo,
    const float* __restrict__ bm2F,
    const float* __restrict__ goF, const float* __restrict__ boF,
    const int* __restrict__ flags, void* __restrict__ out)
{
  // LDS: [0,32768) Y during head loop: tile t at t*8192 (hi 4KB | lo 4KB)
  //                h1 during LN phase: hi rows [0,16384), lo [16384,32768)
  //                (row n_l at +n_l*256, swizzled)
  //      [32768,40960) pS f32[16][128] per-tile transient
  __shared__ __align__(16) char smem[40960];
  float* pS = (float*)(smem + 32768);

  const int tid = threadIdx.x;
  const int f = flags[0];
  const u16* x16 = (const u16*)xv; const float* x32 = (const float*)xv;
  const int lbase = blockIdx.x * NB;
  const int nbase = n0 + lbase;

  const int lane = tid & 63;
  const int wv = tid >> 6;
  const int m16 = lane & 15;
  const int lg = lane >> 4;
  const int colbase = wv * 32;
  const int jA = colbase + m16;

  int aoff[4];
  #pragma unroll
  for (int kk = 0; kk < 4; kk++){
    int sw = (m16 & 7) << 4;
    aoff[kk] = m16*256 + ((kk*64 + lg*16) ^ sw);
  }

  auto LDW = [&](const u16* Whi, const u16* Wlo, int h, bf16x8 (*w)[4]){
    #pragma unroll
    for (int kk = 0; kk < 4; kk++){
      size_t bi0 = ((size_t)(h*C_DIM + jA) << 7) + kk*32 + lg*8;
      w[kk][0] = *(const bf16x8*)(Whi + bi0);
      w[kk][1] = *(const bf16x8*)(Wlo + bi0);
      w[kk][2] = *(const bf16x8*)(Whi + bi0 + 2048);
      w[kk][3] = *(const bf16x8*)(Wlo + bi0 + 2048);
    }
  };

  f32x4 P0[4], P1[4];
  #pragma unroll
  for (int t = 0; t < 4; t++){
    P0[t] = (f32x4){0,0,0,0};
    P1[t] = (f32x4){0,0,0,0};
  }

  bf16x8 w[4][4];
  for (int h = 0; h < 8; h++){
    LDW(WcT_hi, WcT_lo, h, w);        // mm1 weights
    float bc0 = bcF[h*C_DIM + colbase + m16];
    float bc1 = bcF[h*C_DIM + colbase + 16 + m16];

    // mm1 over 4 tiles -> Y; A-fragments streamed from global agg
    #pragma unroll
    for (int t = 0; t < 4; t++){
      const char* arow = (const char*)aggBuf +
          (((size_t)((lbase + t*16 + m16)*8 + h)) << 9);
      f32x4 a0 = {0,0,0,0}, a1 = {0,0,0,0};
      #pragma unroll
      for (int kk = 0; kk < 4; kk++){
        bf16x8 ah = *(const bf16x8*)(arow + kk*64 + lg*16);
        bf16x8 al = *(const bf16x8*)(arow + kk*64 + lg*16 + 256);
        a0 = mfma16(ah, w[kk][0], a0);
        a0 = mfma16(ah, w[kk][1], a0);
        a0 = mfma16(al, w[kk][0], a0);
        a1 = mfma16(ah, w[kk][2], a1);
        a1 = mfma16(ah, w[kk][3], a1);
        a1 = mfma16(al, w[kk][2], a1);
      }
      #pragma unroll
      for (int r = 0; r < 4; r++){
        int row = lg*4 + r;
        int rs = row*256;
        int sw2 = (row & 7) << 4;
        {
          float v = fmaxf(a0[r] + bc0, 0.f);
          u16 hi = f2bu(v); u16 lo = f2bu(v - bu2f(hi));
          int bo = rs + (((colbase + m16)*2) ^ sw2);
          *(u16*)(smem + t*8192 + bo) = hi;
          *(u16*)(smem + t*8192 + 4096 + bo) = lo;
        }
        {
          float v = fmaxf(a1[r] + bc1, 0.f);
          u16 hi = f2bu(v); u16 lo = f2bu(v - bu2f(hi));
          int bo = rs + (((colbase + 16 + m16)*2) ^ sw2);
          *(u16*)(smem + t*8192 + bo) = hi;
          *(u16*)(smem + t*8192 + 4096 + bo) = lo;
        }
      }
    }
    LDW(Wm1T_hi, Wm1T_lo, h, w);      // mm2 weights (latency hidden by barrier)
    __syncthreads();                  // Y writes drained

    // mm2 over 4 tiles, accumulate P across heads
    #pragma unroll
    for (int t = 0; t < 4; t++){
      #pragma unroll
      for (int kk = 0; kk < 4; kk++){
        bf16x8 yh = *(const bf16x8*)(smem + t*8192 + aoff[kk]);
        bf16x8 yl = *(const bf16x8*)(smem + t*8192 + 4096 + aoff[kk]);
        P0[t] = mfma16(yh, w[kk][0], P0[t]);
        P0[t] = mfma16(yh, w[kk][1], P0[t]);
        P0[t] = mfma16(yl, w[kk][0], P0[t]);
        P1[t] = mfma16(yh, w[kk][2], P1[t]);
        P1[t] = mfma16(yh, w[kk][3], P1[t]);
        P1[t] = mfma16(yl, w[kk][2], P1[t]);
      }
    }
    __syncthreads();                  // Y reads done before next head's writes
  }

  // ---- mlp1 (tiled): per tile, P -> pS(8KB) -> LN -> h1 into [0,32KB) ----
  #pragma unroll
  for (int t = 0; t < 4; t++){
    #pragma unroll
    for (int r = 0; r < 4; r++){
      int row = lg*4 + r;
      pS[row*C_DIM + colbase + m16]      = P0[t][r];
      pS[row*C_DIM + colbase + 16 + m16] = P1[t][r];
    }
    __syncthreads();
    for (int g = 0; g < 4; g++){
      int rl = wv*4 + g;              // row within tile
      int n_l = t*16 + rl;
      int nc = min(nbase + n_l, N_NODES-1);
      int bi = clampi(batch[nc], 0, B_DIM-1);
      float v0 = pS[rl*C_DIM + lane]      + bm1F[lane]      + proj[bi*C_DIM + lane];
      float v1 = pS[rl*C_DIM + 64 + lane] + bm1F[64 + lane] + proj[bi*C_DIM + 64 + lane];
      float mean = wave_sum64(v0 + v1) * (1.f/C_DIM);
      float d0 = v0 - mean, d1 = v1 - mean;
      float var = wave_sum64(d0*d0 + d1*d1) * (1.f/C_DIM);
      float rinv = rsqrtf(var + 1e-5f);
      float h0 = fmaxf(d0*rinv*ghF[lane]      + bhF[lane], 0.f);
      float h1v = fmaxf(d1*rinv*ghF[64+lane]  + bhF[64+lane], 0.f);
      int sw3 = (n_l & 7) << 4;
      {
        u16 hi = f2bu(h0); u16 lo = f2bu(h0 - bu2f(hi));
        int bo = n_l*256 + ((lane*2) ^ sw3);
        *(u16*)(smem + bo) = hi;
        *(u16*)(smem + 16384 + bo) = lo;
      }
      {
        u16 hi = f2bu(h1v); u16 lo = f2bu(h1v - bu2f(hi));
        int bo = n_l*256 + (((64+lane)*2) ^ sw3);
        *(u16*)(smem + bo) = hi;
        *(u16*)(smem + 16384 + bo) = lo;
      }
    }
    __syncthreads();
  }

  // ---- mlp2 (tiled): MFMA from h1, pS scratch, residual + final LN -> out ----
  LDW(Wm2T_hi, Wm2T_lo, 0, w);
  #pragma unroll
  for (int t = 0; t < 4; t++){
    f32x4 A0 = {0,0,0,0}, A1 = {0,0,0,0};
    #pragma unroll
    for (int kk = 0; kk < 4; kk++){
      bf16x8 yh = *(const bf16x8*)(smem + t*4096 + aoff[kk]);
      bf16x8 yl = *(const bf16x8*)(smem + 16384 + t*4096 + aoff[kk]);
      A0 = mfma16(yh, w[kk][0], A0);
      A0 = mfma16(yh, w[kk][1], A0);
      A0 = mfma16(yl, w[kk][0], A0);
      A1 = mfma16(yh, w[kk][2], A1);
      A1 = mfma16(yh, w[kk][3], A1);
      A1 = mfma16(yl, w[kk][2], A1);
    }
    __syncthreads();                  // prior tile's pS LN reads drained
    #pragma unroll
    for (int r = 0; r < 4; r++){
      int row = lg*4 + r;
      pS[row*C_DIM + colbase + m16]      = A0[r];
      pS[row*C_DIM + colbase + 16 + m16] = A1[r];
    }
    __syncthreads();
    for (int g = 0; g < 4; g++){
      int rl = wv*4 + g;
      int n_l = t*16 + rl;
      int n = nbase + n_l;
      int nc = min(n, N_NODES-1);
      float x0 = f ? bu2f(x16[(size_t)nc*C_DIM + lane])      : x32[(size_t)nc*C_DIM + lane];
      float x1 = f ? bu2f(x16[(size_t)nc*C_DIM + 64 + lane]) : x32[(size_t)nc*C_DIM + 64 + lane];
      float v0 = pS[rl*C_DIM + lane]      + bm2F[lane]      + x0;
      float v1 = pS[rl*C_DIM + 64 + lane] + bm2F[64 + lane] + x1;
      float mean = wave_sum64(v0 + v1) * (1.f/C_DIM);
      float d0 = v0 - mean, d1 = v1 - mean;
      float var = wave_sum64(d0*d0 + d1*d1) * (1.f/C_DIM);
      float rinv = rsqrtf(var + 1e-5f);
      if (lbase + n_l < ncnt){
        stf(out, (size_t)n*C_DIM + lane,      f, d0*rinv*goF[lane]      + boF[lane]);
        stf(out, (size_t)n*C_DIM + 64 + lane, f, d1*rinv*goF[64+lane]   + boF[64+lane]);
      }
    }
  }
}

// ---------------- launcher ----------------

extern "C" void kernel_launch(void* const* d_in, const int* in_sizes, int n_in,
                              void* d_out, int out_size, void* d_ws, size_t ws_size,
                              hipStream_t stream)
{
  const void* x      = d_in[0];
  const void* in1    = d_in[1];
  const void* in2    = d_in[2];
  const int*  batch  = (const int*)d_in[3];
  (void)in_sizes; (void)n_in; (void)out_size;

  char* ws = (char*)d_ws;
  size_t off = 0;
  auto alloc = [&](size_t nbytes)->char*{
    char* p = ws + off;
    off += (nbytes + 255) & ~(size_t)255;
    return p;
  };
  int*   flags = (int*)alloc(8);
  float* arena = (float*)alloc((size_t)ARENA_TOTAL*4);
  int* hist    = (int*)alloc((size_t)N_NODES*4);          // becomes cursor after scan
  int* offsets = (int*)alloc((size_t)(N_NODES+1)*4);
  int* bsums   = (int*)alloc((size_t)SCAN_BLK*4);
  ERec* sortedRec = (ERec*)alloc((size_t)N_EDGES*16);
  float* proj   = (float*)alloc((size_t)B_DIM*C_DIM*4);
  float* xsum   = (float*)alloc((size_t)B_DIM*C_DIM*4);
  int*   counts = (int*)alloc((size_t)B_DIM*4);
  float* tokens = (float*)alloc((size_t)B_DIM*L_DIM*C_DIM*4);  // reused as Bp
  float* x_in   = (float*)alloc((size_t)B_DIM*L_DIM*D_DIM*4);  // reused as dtb
  float* x_c    = (float*)alloc((size_t)B_DIM*L_DIM*D_DIM*4);
  float* Cp     = (float*)alloc((size_t)B_DIM*L_DIM*S_DIM*4);
  float* z_last = (float*)alloc((size_t)B_DIM*D_DIM*4);
  float* y_last = (float*)alloc((size_t)B_DIM*D_DIM*4);
  u16* WcT_hi  = (u16*)alloc((size_t)8*C_DIM*C_DIM*2);
  u16* WcT_lo  = (u16*)alloc((size_t)8*C_DIM*C_DIM*2);
  u16* Wm1T_hi = (u16*)alloc((size_t)8*C_DIM*C_DIM*2);
  u16* Wm1T_lo = (u16*)alloc((size_t)8*C_DIM*C_DIM*2);
  u16* Wm2T_hi = (u16*)alloc((size_t)C_DIM*C_DIM*2);
  u16* Wm2T_lo = (u16*)alloc((size_t)C_DIM*C_DIM*2);

  // dynamic chunking: give all remaining workspace to aggBuf (4 KB/node)
  size_t avail = (ws_size > off + 4096) ? (ws_size - off - 4096) : 0;
  long long cn = (long long)(avail / 4096);
  cn &= ~63LL;
  if (cn > MAX_CHUNK) cn = MAX_CHUNK;
  if (cn < 64) cn = 16704;            // fallback
  const int chunkN = (int)cn;
  u16* aggBuf = (u16*)alloc((size_t)chunkN * 4096);

  float* Bp  = tokens;
  float* dtb = x_in;

  // weight arena views (match kCum)
  float* WeF   = arena + 0;      float* beF   = arena + 2048;
  float* WcF   = arena + 3072;   float* bcF   = arena + 134144;
  float* WihF  = arena + 135168; float* WhhF  = arena + 184320;
  float* bihF  = arena + 233472; float* bhhF  = arena + 233856;
  float* WinF  = arena + 234240; float* cwF   = arena + 299776;
  float* cbF   = arena + 300800; float* WxF   = arena + 301056;
  float* WdtF  = arena + 368640; float* bdtF  = arena + 370688;
  float* AlF   = arena + 370944; float* DpF   = arena + 403712;
  float* WoutF = arena + 403968; float* gmF   = arena + 436736;
  float* bmF   = arena + 436864; float* Wm1F  = arena + 436992;
  float* bm1F  = arena + 584448; float* ghF   = arena + 584576;
  float* bhF   = arena + 584704; float* Wm2F  = arena + 584832;
  float* bm2F  = arena + 601216; float* goF   = arena + 601344;
  float* boF   = arena + 601472;

  // 0) detect dtype + edge-input order
  detect_kernel<<<1, 64, 0, stream>>>((const unsigned*)d_in[19],
                                      (const unsigned*)in1, (const unsigned*)in2, flags);

  // 1) all weight converts in one launch, then MFMA transpose/split
  Ptrs ptrs;
  for (int i = 0; i < K_SEG; i++) ptrs.p[i] = d_in[4 + i];
  cvt_all_kernel<<<(ARENA_TOTAL + 255)/256, 256, 0, stream>>>(ptrs, arena, flags);
  wtrans_kernel<<<(8*C_DIM*C_DIM + 255)/256, 256, 0, stream>>>(
      WcF, Wm1F, Wm2F, WcT_hi, WcT_lo, Wm1T_hi, Wm1T_lo, Wm2T_hi, Wm2T_lo);

  // 2) counting sort of edges by dst (3-phase parallel scan + pre-gather)
  hipMemsetAsync(hist, 0, (size_t)N_NODES*4, stream);
  hist_kernel<<<(N_EDGES + 255)/256, 256, 0, stream>>>((const int*)in1, (const int*)in2, flags, hist);
  scan1_kernel<<<SCAN_BLK, 1024, 0, stream>>>(hist, offsets, bsums);
  scan2_kernel<<<1, 64, 0, stream>>>(bsums, offsets);
  scan3_kernel<<<SCAN_BLK, 1024, 0, stream>>>(offsets, hist, bsums);
  perm_kernel<<<(N_EDGES + 255)/256, 256, 0, stream>>>(in1, in2, flags, hist, sortedRec);

  // 3) sequential path
  hipMemsetAsync(xsum, 0, (size_t)B_DIM*C_DIM*4 + 256, stream);  // xsum + counts
  pool_kernel<<<(N_NODES + 31)/32, 128, 0, stream>>>(x, batch, xsum, counts, flags);
  gru_kernel<<<B_DIM, 384, 0, stream>>>(xsum, counts, WihF, bihF, WhhF, bhhF, tokens);
  token_proj_kernel<<<B_DIM*L_DIM, 256, 0, stream>>>(tokens, WinF, x_in, z_last);
  xproj_kernel<<<B_DIM*L_DIM, 256, 0, stream>>>(x_in, cwF, cbF, WxF, WdtF, bdtF, dtb, Bp, Cp, x_c);
  ssm_kernel<<<(B_DIM*D_DIM)/4, 256, 0, stream>>>(dtb, Bp, Cp, x_c, AlF, DpF, z_last, y_last);
  xm_kernel<<<B_DIM, 128, 0, stream>>>(y_last, WoutF, gmF, bmF, Wm1F + 8*C_DIM*C_DIM, proj);

  // 4) chunked (ideally 1 chunk): gather -> agg; fused (global-agg, 3/CU) -> d_out
  for (int n0 = 0; n0 < N_NODES; n0 += chunkN){
    int ncnt = min(chunkN, N_NODES - n0);
    int nsets = (ncnt + NPW - 1) / NPW;
    int nwaves = 2 * nsets;
    gather_kernel<<<(nwaves + 3)/4, 256, 0, stream>>>(
        x, sortedRec, offsets, WeF, beF, flags, aggBuf, n0, ncnt);
    fused_kernel<<<(ncnt + NB - 1)/NB, 256, 0, stream>>>(
        x, aggBuf, n0, ncnt, WcT_hi, WcT_lo, bcF, Wm1T_hi, Wm1T_lo, bm1F,
        proj, batch, ghF, bhF, Wm2T_hi, Wm2T_lo, bm2F, goF, boF, flags, d_out);
  }
}

// Round 16
// 807.802 us; speedup vs baseline: 1.0857x; 1.0857x over previous
//
#include <hip/hip_runtime.h>
#include <hip/hip_bf16.h>

#define N_NODES 50000
#define N_EDGES 640000
#define C_DIM 128
#define B_DIM 64
#define L_DIM 32
#define D_DIM 256
#define S_DIM 128
#define R_DIM 8
#define K_CONV 4
#define NPW 8         // nodes per gather wave
#define NB 48         // nodes per fused block (3 MFMA tiles)
#define MAX_CHUNK 50064
#define SCAN_BLK 49   // ceil(50000/1024)

typedef unsigned short u16;
typedef __attribute__((ext_vector_type(8))) short bf16x8;   // 8 bf16 = 4 VGPRs
typedef __attribute__((ext_vector_type(4))) float f32x4;

struct __align__(16) ERec { int s; float a0, a1; int pad; };

__device__ __forceinline__ float bu2f(u16 u){ return __uint_as_float(((unsigned)u) << 16); }
__device__ __forceinline__ u16 f2bu(float f){
  __hip_bfloat16 h = __float2bfloat16(f);
  return *reinterpret_cast<u16*>(&h);
}
__device__ __forceinline__ float sigmoidf_(float x){ return 1.f/(1.f + expf(-x)); }
__device__ __forceinline__ int clampi(int v, int lo, int hi){ return max(lo, min(v, hi)); }
__device__ __forceinline__ float ldf(const void* p, size_t i, int f){
  return f ? bu2f(((const u16*)p)[i]) : ((const float*)p)[i];
}
__device__ __forceinline__ void stf(void* p, size_t i, int f, float v){
  if (f) ((u16*)p)[i] = f2bu(v); else ((float*)p)[i] = v;
}
__device__ __forceinline__ f32x4 mfma16(bf16x8 a, bf16x8 b, f32x4 c){
  return __builtin_amdgcn_mfma_f32_16x16x32_bf16(a, b, c, 0, 0, 0);
}
__device__ __forceinline__ float wave_sum64(float v){
  #pragma unroll
  for (int off = 32; off; off >>= 1) v += __shfl_xor(v, off);
  return v;
}

// weight arena layout (element offsets); 27 segments in d_in[4..30] order
constexpr int K_SEG = 27;
constexpr int kCum[K_SEG+1] = {
  0, 2048, 3072, 134144, 135168, 184320, 233472, 233856, 234240, 299776,
  300800, 301056, 368640, 370688, 370944, 403712, 403968, 436736, 436864,
  436992, 584448, 584576, 584704, 584832, 601216, 601344, 601472, 601600 };
#define ARENA_TOTAL 601600

struct Ptrs { const void* p[K_SEG]; };

// ---------------- detection (64-lane parallel) ----------------

__global__ void detect_kernel(const unsigned* dp_bits, const unsigned* cand1,
                              const unsigned* cand2, int* flags){
  int lane = threadIdx.x & 63;
  unsigned idx = (unsigned)((lane * 9973u) % (unsigned)N_EDGES);
  int v1 = (cand1[idx] < (unsigned)N_NODES) ? 1 : 0;
  int v2 = (cand2[idx] < (unsigned)N_NODES) ? 1 : 0;
  unsigned long long m1 = __ballot(v1);
  unsigned long long m2 = __ballot(v2);
  if (lane == 0){
    flags[0] = (dp_bits[0] == 0x3F803F80u) ? 1 : 0;
    flags[1] = (__popcll(m1) > __popcll(m2)) ? 1 : 0;   // 1 => d_in[1] is edge_index
  }
}

// ---------------- fused weight-convert ----------------

__global__ __launch_bounds__(256) void cvt_all_kernel(Ptrs ptrs, float* arena,
                                                      const int* flags){
  int i = blockIdx.x*256 + threadIdx.x;
  if (i >= ARENA_TOTAL) return;
  int lo = 0, hi = K_SEG;
  #pragma unroll
  for (int it = 0; it < 5; it++){
    int mid = (lo + hi) >> 1;
    if (i >= kCum[mid]) lo = mid; else hi = mid;
  }
  int elem = i - kCum[lo];
  const void* sp = ptrs.p[lo];
  arena[i] = flags[0] ? bu2f(((const u16*)sp)[elem]) : ((const float*)sp)[elem];
}

// ---------------- weight transpose + bf16 hi/lo split for MFMA ----------------

__global__ __launch_bounds__(256) void wtrans_kernel(
    const float* __restrict__ WcF, const float* __restrict__ Wm1F,
    const float* __restrict__ Wm2F,
    u16* __restrict__ WcT_hi, u16* __restrict__ WcT_lo,
    u16* __restrict__ Wm1T_hi, u16* __restrict__ Wm1T_lo,
    u16* __restrict__ Wm2T_hi, u16* __restrict__ Wm2T_lo)
{
  int i = blockIdx.x*256 + threadIdx.x;
  if (i >= 8*C_DIM*C_DIM) return;
  int h = i >> 14, j = (i >> 7) & 127, k = i & 127;
  {
    float w = WcF[(h<<14) + (k<<7) + j];
    u16 hi = f2bu(w); u16 lo = f2bu(w - bu2f(hi));
    WcT_hi[i] = hi; WcT_lo[i] = lo;
  }
  {
    float w = Wm1F[((size_t)((h<<7) + k) << 7) + j];
    u16 hi = f2bu(w); u16 lo = f2bu(w - bu2f(hi));
    Wm1T_hi[i] = hi; Wm1T_lo[i] = lo;
  }
  if (i < C_DIM*C_DIM){
    int j2 = i >> 7, k2 = i & 127;
    float w = Wm2F[(k2<<7) + j2];
    u16 hi = f2bu(w); u16 lo = f2bu(w - bu2f(hi));
    Wm2T_hi[i] = hi; Wm2T_lo[i] = lo;
  }
}

// ---------------- counting sort of edges by dst ----------------

__global__ void hist_kernel(const int* __restrict__ eiA, const int* __restrict__ eiB,
                            const int* __restrict__ flags, int* __restrict__ hist){
  const int* dst = (flags[1] ? eiA : eiB) + N_EDGES;
  int e = blockIdx.x*256 + threadIdx.x;
  if (e >= N_EDGES) return;
  int d = clampi(dst[e], 0, N_NODES-1);
  atomicAdd(&hist[d], 1);
}

__global__ __launch_bounds__(1024) void scan1_kernel(const int* __restrict__ hist,
                                                     int* __restrict__ tmp,
                                                     int* __restrict__ bsums){
  __shared__ int buf[1024];
  int b = blockIdx.x, tid = threadIdx.x;
  int i = b*1024 + tid;
  int v = (i < N_NODES) ? hist[i] : 0;
  buf[tid] = v;
  __syncthreads();
  for (int off = 1; off < 1024; off <<= 1){
    int t = (tid >= off) ? buf[tid-off] : 0;
    __syncthreads();
    buf[tid] += t;
    __syncthreads();
  }
  if (i < N_NODES) tmp[i] = buf[tid];       // inclusive
  if (tid == 1023) bsums[b] = buf[1023];
}

__global__ void scan2_kernel(int* __restrict__ bsums, int* __restrict__ offsets){
  if (threadIdx.x == 0){
    int run = 0;
    for (int b = 0; b < SCAN_BLK; b++){ int v = bsums[b]; bsums[b] = run; run += v; }
    offsets[N_NODES] = run;
  }
}

__global__ __launch_bounds__(1024) void scan3_kernel(int* __restrict__ offsets,
                                                     int* __restrict__ hist,
                                                     const int* __restrict__ bsums){
  int b = blockIdx.x, tid = threadIdx.x;
  int i = b*1024 + tid;
  if (i >= N_NODES) return;
  int incl = offsets[i];
  int h = hist[i];
  int excl = incl - h + bsums[b];
  offsets[i] = excl;
  hist[i] = excl;       // cursor copy for perm_kernel
}

__global__ void perm_kernel(const void* __restrict__ in1, const void* __restrict__ in2,
                            const int* __restrict__ flags, int* __restrict__ cursor,
                            ERec* __restrict__ sortedRec){
  int e = blockIdx.x*256 + threadIdx.x;
  if (e >= N_EDGES) return;
  const int f1 = flags[1], f = flags[0];
  const int* ei  = (const int*)(f1 ? in1 : in2);
  const void* eav = f1 ? in2 : in1;
  int d = clampi(ei[N_EDGES + e], 0, N_NODES-1);
  int s = clampi(ei[e], 0, N_NODES-1);
  float a0, a1;
  if (f){ const u16* e16 = (const u16*)eav; a0 = bu2f(e16[2*e]); a1 = bu2f(e16[2*e+1]); }
  else  { const float* e32 = (const float*)eav; a0 = e32[2*e]; a1 = e32[2*e+1]; }
  int pos = atomicAdd(&cursor[d], 1);
  pos = clampi(pos, 0, N_EDGES-1);
  ERec r; r.s = s; r.a0 = a0; r.a1 = a1; r.pad = 0;
  sortedRec[pos] = r;
}

// ---------------- edge gather -> agg (bf16 hi/lo planes) ----------------
// Wave = (chalf, 8-node set). Weights stay in VGPRs across all 8 nodes; each
// wave owns its nodes' channel-half completely -> no LDS, no barriers.
// Edge record packed 16B (one dwordx4 per edge). agg: [nl][h][{hi,lo}][128].

__global__ __launch_bounds__(256, 8) void gather_kernel(
    const void* __restrict__ xv, const ERec* __restrict__ sortedRec,
    const int* __restrict__ offsets,
    const float* __restrict__ WeF, const float* __restrict__ beF,
    const int* __restrict__ flags, u16* __restrict__ aggBuf,
    int n0, int ncnt)
{
  int w = blockIdx.x*4 + (threadIdx.x >> 6);
  int nsets = (ncnt + NPW - 1) / NPW;
  if (w >= 2*nsets) return;
  int chalf = w & 1;
  int nset = w >> 1;
  int lane = threadIdx.x & 63;
  int c = lane + chalf*64;
  const int f = flags[0];
  const u16* x16 = (const u16*)xv; const float* x32 = (const float*)xv;

  float we0[8], we1[8], beh[8];
  #pragma unroll
  for (int h = 0; h < 8; h++){
    we0[h] = WeF[h*2*C_DIM + c];
    we1[h] = WeF[h*2*C_DIM + C_DIM + c];
    beh[h] = beF[h*C_DIM + c];
  }

  auto LD = [&](int q, float& xr, float2& er){
    ERec r = sortedRec[q];          // one 16B load
    er = make_float2(r.a0, r.a1);
    int idx = r.s*C_DIM + c;
    xr = f ? bu2f(x16[idx]) : x32[idx];
  };

  int nl_end = min(nset*NPW + NPW, ncnt);
  for (int nl = nset*NPW; nl < nl_end; nl++){
    int n = n0 + nl;
    int q0 = offsets[n];
    int cnt = offsets[n+1] - q0;

    float acc[8] = {0,0,0,0,0,0,0,0};
    float xA=0.f, xB=0.f, xC=0.f, xD=0.f;
    float2 eA=make_float2(0,0), eB=make_float2(0,0), eC=make_float2(0,0), eD=make_float2(0,0);
    if (cnt > 0) LD(q0+0, xA, eA);
    if (cnt > 1) LD(q0+1, xB, eB);
    if (cnt > 2) LD(q0+2, xC, eC);
    if (cnt > 3) LD(q0+3, xD, eD);

    for (int j = 0; j < cnt; j += 4){
      float ux0=xA, ux1=xB, ux2=xC, ux3=xD;
      float2 ue0=eA, ue1=eB, ue2=eC, ue3=eD;
      if (j+4 < cnt) LD(q0+j+4, xA, eA);
      if (j+5 < cnt) LD(q0+j+5, xB, eB);
      if (j+6 < cnt) LD(q0+j+6, xC, eC);
      if (j+7 < cnt) LD(q0+j+7, xD, eD);
      #pragma unroll
      for (int h = 0; h < 8; h++)
        acc[h] += fmaxf(fmaf(ue0.x, we0[h], fmaf(ue0.y, we1[h], ux0 + beh[h])), 0.f);
      if (j+1 < cnt){
        #pragma unroll
        for (int h = 0; h < 8; h++)
          acc[h] += fmaxf(fmaf(ue1.x, we0[h], fmaf(ue1.y, we1[h], ux1 + beh[h])), 0.f);
      }
      if (j+2 < cnt){
        #pragma unroll
        for (int h = 0; h < 8; h++)
          acc[h] += fmaxf(fmaf(ue2.x, we0[h], fmaf(ue2.y, we1[h], ux2 + beh[h])), 0.f);
      }
      if (j+3 < cnt){
        #pragma unroll
        for (int h = 0; h < 8; h++)
          acc[h] += fmaxf(fmaf(ue3.x, we0[h], fmaf(ue3.y, we1[h], ux3 + beh[h])), 0.f);
      }
    }

    int base = nl*2048 + c;
    #pragma unroll
    for (int h = 0; h < 8; h++){
      u16 hv = f2bu(acc[h]);
      u16 lv = f2bu(acc[h] - bu2f(hv));
      aggBuf[base + h*256]       = hv;
      aggBuf[base + h*256 + 128] = lv;
    }
  }
}

// ---------------- pooling ----------------

__global__ __launch_bounds__(128) void pool_kernel(
    const void* __restrict__ xv, const int* __restrict__ batch,
    float* __restrict__ xsum, int* __restrict__ counts, const int* __restrict__ flags)
{
  int c = threadIdx.x;
  int f = flags[0];
  int n0 = blockIdx.x * 32;
  int nend = min(n0 + 32, N_NODES);
  float acc = 0.f; int cnt = 0;
  int curb = clampi(batch[n0], 0, B_DIM-1);
  for (int n = n0; n < nend; n++){
    int b = clampi(batch[n], 0, B_DIM-1);
    if (b != curb){
      atomicAdd(&xsum[curb*C_DIM + c], acc);
      if (c == 0) atomicAdd(&counts[curb], cnt);
      acc = 0.f; cnt = 0; curb = b;
    }
    acc += ldf(xv, (size_t)n*C_DIM + c, f);
    cnt++;
  }
  atomicAdd(&xsum[curb*C_DIM + c], acc);
  if (c == 0) atomicAdd(&counts[curb], cnt);
}

// ---------------- GRU (Whh column register-cached) ----------------

__global__ __launch_bounds__(384, 1) void gru_kernel(
    const float* __restrict__ xsum, const int* __restrict__ counts,
    const float* __restrict__ Wih, const float* __restrict__ bih,
    const float* __restrict__ Whh, const float* __restrict__ bhh,
    float* __restrict__ tokens)
{
  int b = blockIdx.x, j = threadIdx.x;
  __shared__ float xm[C_DIM], h[C_DIM], gh[3*C_DIM], sgi[3*C_DIM];
  __shared__ float mxS;
  if (j == 0){
    int m = 1;
    for (int bb = 0; bb < B_DIM; bb++) m = max(m, counts[bb]);
    mxS = (float)m;
  }
  __syncthreads();
  if (j < C_DIM){ xm[j] = xsum[b*C_DIM + j] / mxS; h[j] = 0.f; }
  __syncthreads();

  {
    float a0=0.f, a1=0.f, a2=0.f, a3=0.f;
    for (int k = 0; k < C_DIM; k += 4){
      a0 = fmaf(xm[k],   Wih[(k  )*384 + j], a0);
      a1 = fmaf(xm[k+1], Wih[(k+1)*384 + j], a1);
      a2 = fmaf(xm[k+2], Wih[(k+2)*384 + j], a2);
      a3 = fmaf(xm[k+3], Wih[(k+3)*384 + j], a3);
    }
    sgi[j] = bih[j] + ((a0 + a1) + (a2 + a3));
  }

  float w[C_DIM];
  #pragma unroll
  for (int k = 0; k < C_DIM; k++) w[k] = Whh[k*384 + j];
  float bh = bhh[j];
  __syncthreads();

  float g_ir = 0.f, g_iz = 0.f, g_in = 0.f;
  if (j < C_DIM){ g_ir = sgi[j]; g_iz = sgi[C_DIM + j]; g_in = sgi[2*C_DIM + j]; }

  for (int t = 0; t < L_DIM; t++){
    float a0=0.f, a1=0.f, a2=0.f, a3=0.f;
    #pragma unroll
    for (int k = 0; k < C_DIM; k += 4){
      a0 = fmaf(h[k],   w[k],   a0);
      a1 = fmaf(h[k+1], w[k+1], a1);
      a2 = fmaf(h[k+2], w[k+2], a2);
      a3 = fmaf(h[k+3], w[k+3], a3);
    }
    gh[j] = bh + ((a0 + a1) + (a2 + a3));
    __syncthreads();
    if (j < C_DIM){
      float r  = sigmoidf_(g_ir + gh[j]);
      float z  = sigmoidf_(g_iz + gh[C_DIM + j]);
      float nn = tanhf(g_in + r*gh[2*C_DIM + j]);
      float hn = (1.f - z)*nn + z*h[j];
      h[j] = hn;
      tokens[((size_t)b*L_DIM + t)*C_DIM + j] = hn;
    }
    __syncthreads();
  }
}

// ---------------- token projection (Win) ----------------

__global__ __launch_bounds__(256) void token_proj_kernel(
    const float* __restrict__ tokens, const float* __restrict__ Win,
    float* __restrict__ x_in, float* __restrict__ z_last)
{
  int row = blockIdx.x;
  int d = threadIdx.x;
  __shared__ float tok[C_DIM];
  if (d < C_DIM) tok[d] = tokens[(size_t)row*C_DIM + d];
  __syncthreads();
  float acc = 0.f;
  for (int k = 0; k < C_DIM; k++) acc = fmaf(tok[k], Win[k*512 + d], acc);
  x_in[(size_t)row*D_DIM + d] = acc;
  if ((row & (L_DIM-1)) == L_DIM-1){
    float acc2 = 0.f;
    for (int k = 0; k < C_DIM; k++) acc2 = fmaf(tok[k], Win[k*512 + D_DIM + d], acc2);
    z_last[(row >> 5)*D_DIM + d] = acc2;
  }
}

// ---------------- xproj ----------------

__global__ __launch_bounds__(256) void xproj_kernel(
    const float* __restrict__ x_in, const float* __restrict__ cw,
    const float* __restrict__ cb, const float* __restrict__ Wx,
    const float* __restrict__ Wdt, const float* __restrict__ bdt,
    float* __restrict__ dt, float* __restrict__ Bp, float* __restrict__ Cp,
    float* __restrict__ x_c)
{
  int row = blockIdx.x; int tid = threadIdx.x;
  int t = row & (L_DIM-1);
  __shared__ float xr[D_DIM];
  __shared__ float dtr[R_DIM];
  float acc0 = cb[tid];
  #pragma unroll
  for (int k = 0; k < K_CONV; k++){
    int tt = t + k - (K_CONV-1);
    if (tt >= 0) acc0 = fmaf(cw[tid*K_CONV + k], x_in[(size_t)(row + tt - t)*D_DIM + tid], acc0);
  }
  float xcv = acc0 * sigmoidf_(acc0);
  x_c[(size_t)row*D_DIM + tid] = xcv;
  xr[tid] = xcv;
  __syncthreads();
  float acc = 0.f;
  #pragma unroll 4
  for (int k = 0; k < D_DIM; k++) acc = fmaf(xr[k], Wx[k*264 + tid], acc);
  if (tid < R_DIM)              dtr[tid] = acc;
  else if (tid < R_DIM+S_DIM)   Bp[(size_t)row*S_DIM + tid - R_DIM] = acc;
  else                          Cp[(size_t)row*S_DIM + tid - (R_DIM+S_DIM)] = acc;
  if (tid < 264 - D_DIM){
    float acc2 = 0.f;
    #pragma unroll 4
    for (int k = 0; k < D_DIM; k++) acc2 = fmaf(xr[k], Wx[k*264 + D_DIM + tid], acc2);
    Cp[(size_t)row*S_DIM + (D_DIM - (R_DIM+S_DIM)) + tid] = acc2;
  }
  __syncthreads();
  float a = bdt[tid];
  #pragma unroll
  for (int r = 0; r < R_DIM; r++) a = fmaf(dtr[r], Wdt[r*D_DIM + tid], a);
  dt[(size_t)row*D_DIM + tid] = (a > 20.f) ? a : log1pf(expf(a));
}

// ---------------- SSM scan ----------------

__global__ __launch_bounds__(256) void ssm_kernel(
    const float* __restrict__ dt, const float* __restrict__ Bp,
    const float* __restrict__ Cp, const float* __restrict__ x_c,
    const float* __restrict__ A_log, const float* __restrict__ Dp_,
    const float* __restrict__ z_last, float* __restrict__ y_last)
{
  int wid = (blockIdx.x*256 + threadIdx.x) >> 6;
  int lane = threadIdx.x & 63;
  int b = wid >> 8, d = wid & (D_DIM-1);
  int s0 = lane*2;
  float A0 = -expf(A_log[d*S_DIM + s0]);
  float A1 = -expf(A_log[d*S_DIM + s0 + 1]);
  float h0 = 0.f, h1 = 0.f;
  for (int t = 0; t < L_DIM; t++){
    int row = b*L_DIM + t;
    float dtv = dt[(size_t)row*D_DIM + d];
    float xv  = x_c[(size_t)row*D_DIM + d];
    float bx = dtv * xv;
    float2 Bv = ((const float2*)(Bp + (size_t)row*S_DIM))[lane];
    h0 = fmaf(expf(dtv*A0), h0, bx*Bv.x);
    h1 = fmaf(expf(dtv*A1), h1, bx*Bv.y);
  }
  int row = b*L_DIM + (L_DIM-1);
  float2 Cv = ((const float2*)(Cp + (size_t)row*S_DIM))[lane];
  float y = h0*Cv.x + h1*Cv.y;
  #pragma unroll
  for (int off = 32; off; off >>= 1) y += __shfl_down(y, off);
  if (lane == 0){
    float xc = x_c[(size_t)row*D_DIM + d];
    float yv = y + Dp_[d]*xc;
    float z  = z_last[b*D_DIM + d];
    yv *= z * sigmoidf_(z);
    y_last[b*D_DIM + d] = yv;
  }
}

// ---------------- proj = ln(y_last @ Wout) @ Wm1[8C:] ----------------

__device__ __forceinline__ float block_sum_128(float v, float* red){
  int c = threadIdx.x;
  red[c] = v; __syncthreads();
  if (c < 64) red[c] += red[c+64];
  __syncthreads();
  if (c < 64){
    float r = red[c];
    #pragma unroll
    for (int off = 32; off; off >>= 1) r += __shfl_down(r, off);
    if (c == 0) red[0] = r;
  }
  __syncthreads();
  float out = red[0];
  __syncthreads();
  return out;
}

__global__ __launch_bounds__(128) void xm_kernel(
    const float* __restrict__ y_last, const float* __restrict__ Wout,
    const float* __restrict__ g_m, const float* __restrict__ b_m,
    const float* __restrict__ Wm1x, float* __restrict__ proj)
{
  int b = blockIdx.x, c = threadIdx.x;
  __shared__ float yr[D_DIM];
  __shared__ float red[C_DIM];
  __shared__ float xmr[C_DIM];
  yr[c]        = y_last[b*D_DIM + c];
  yr[C_DIM+c]  = y_last[b*D_DIM + C_DIM + c];
  __syncthreads();
  float acc = 0.f;
  for (int k = 0; k < D_DIM; k++) acc = fmaf(yr[k], Wout[k*C_DIM + c], acc);
  float mean = block_sum_128(acc, red) * (1.f/C_DIM);
  float dv = acc - mean;
  float var = block_sum_128(dv*dv, red) * (1.f/C_DIM);
  float mo = dv*rsqrtf(var + 1e-5f)*g_m[c] + b_m[c];
  xmr[c] = mo;
  __syncthreads();
  float p = 0.f;
  for (int k = 0; k < C_DIM; k++) p = fmaf(xmr[k], Wm1x[k*C_DIM + c], p);
  proj[b*C_DIM + c] = p;
}

// ---------------- fused_kernel: 48 nodes/block, 256 threads, 3 blocks/CU ----------------
// Round-14 structure (coalesced LDS staging + reg weight-prefetch), smaller
// tile count: LDS = agg 24KB + Y 24KB = 48KB -> 3 blocks/CU (12 waves) for
// cross-block hiding of the per-head barrier drains.

__global__ __launch_bounds__(256, 3) void fused_kernel(
    const void* __restrict__ xv, const u16* __restrict__ aggBuf, int n0, int ncnt,
    const u16* __restrict__ WcT_hi, const u16* __restrict__ WcT_lo,
    const float* __restrict__ bcF,
    const u16* __restrict__ Wm1T_hi, const u16* __restrict__ Wm1T_lo,
    const float* __restrict__ bm1F, const float* __restrict__ proj,
    const int* __restrict__ batch,
    const float* __restrict__ ghF, const float* __restrict__ bhF,
    const u16* __restrict__ Wm2T_hi, const u16* __restrict__ Wm2T_lo,
    const float* __restrict__ bm2F,
    const float* __restrict__ goF, const float* __restrict__ boF,
    const int* __restrict__ flags, void* __restrict__ out)
{
  // LDS: [0,24576) agg [3 tiles][16 nodes][512B] swizzled (aliased as pS f32[48][128])
  //      [24576,49152) Y: tile t at 24576+t*8192 (hi 4KB | lo 4KB)
  //                    LN phase: h1_hi rows at 24576+n_l*256, h1_lo at 36864+n_l*256
  __shared__ __align__(16) char smem[49152];
  float* pS = (float*)smem;

  const int tid = threadIdx.x;
  const int f = flags[0];
  const u16* x16 = (const u16*)xv; const float* x32 = (const float*)xv;
  const int lbase = blockIdx.x * NB;
  const int nbase = n0 + lbase;

  const int lane = tid & 63;
  const int wv = tid >> 6;
  const int m16 = lane & 15;
  const int lg = lane >> 4;
  const int colbase = wv * 32;
  const int jA = colbase + m16;

  int ahoff[4], aoff[4];
  #pragma unroll
  for (int kk = 0; kk < 4; kk++){
    int sw = (m16 & 7) << 4;
    ahoff[kk] = m16*512 + ((kk*64 + lg*16) ^ sw);
    aoff[kk]  = m16*256 + ((kk*64 + lg*16) ^ sw);
  }

  // staging map: 1536 16B-units; 6 per thread. i = tid + j*256:
  //   t=i>>9 (0..2), g=(i>>5)&15, u=i&31; node = lbase+t*16+g
  int sg_node[6], sg_u[6], sg_dst[6];
  #pragma unroll
  for (int j = 0; j < 6; j++){
    int i = tid + j*256;
    int t = i >> 9, g = (i >> 5) & 15, u = i & 31;
    sg_node[j] = lbase + t*16 + g;
    sg_u[j] = u << 4;
    sg_dst[j] = t*8192 + (((i & 511) << 4) ^ ((g & 7) << 4));
  }

  bf16x8 sreg[6];
  auto stage_load = [&](int h){
    #pragma unroll
    for (int j = 0; j < 6; j++)
      sreg[j] = *(const bf16x8*)((const char*)aggBuf +
                 (((size_t)sg_node[j]*8 + h) << 9) + sg_u[j]);
  };
  auto stage_commit = [&](){
    #pragma unroll
    for (int j = 0; j < 6; j++) *(bf16x8*)(smem + sg_dst[j]) = sreg[j];
  };
  auto LDW = [&](const u16* Whi, const u16* Wlo, int h, bf16x8 (*w)[4]){
    #pragma unroll
    for (int kk = 0; kk < 4; kk++){
      size_t bi0 = ((size_t)(h*C_DIM + jA) << 7) + kk*32 + lg*8;
      w[kk][0] = *(const bf16x8*)(Whi + bi0);
      w[kk][1] = *(const bf16x8*)(Wlo + bi0);
      w[kk][2] = *(const bf16x8*)(Whi + bi0 + 2048);
      w[kk][3] = *(const bf16x8*)(Wlo + bi0 + 2048);
    }
  };

  // prologue: stage head 0
  stage_load(0);
  stage_commit();
  __syncthreads();

  f32x4 P0[3], P1[3];
  #pragma unroll
  for (int t = 0; t < 3; t++){
    P0[t] = (f32x4){0,0,0,0};
    P1[t] = (f32x4){0,0,0,0};
  }

  bf16x8 w[4][4];
  for (int h = 0; h < 8; h++){
    const bool pf = (h+1 < 8);
    LDW(WcT_hi, WcT_lo, h, w);        // mm1 weights
    if (pf) stage_load(h+1);          // next head's agg -> regs (overlaps mm1)
    float bc0 = bcF[h*C_DIM + colbase + m16];
    float bc1 = bcF[h*C_DIM + colbase + 16 + m16];

    // mm1 over 3 tiles -> Y
    #pragma unroll
    for (int t = 0; t < 3; t++){
      f32x4 a0 = {0,0,0,0}, a1 = {0,0,0,0};
      #pragma unroll
      for (int kk = 0; kk < 4; kk++){
        bf16x8 ah = *(const bf16x8*)(smem + t*8192 + ahoff[kk]);
        bf16x8 al = *(const bf16x8*)(smem + t*8192 + ahoff[kk] + 256);
        a0 = mfma16(ah, w[kk][0], a0);
        a0 = mfma16(ah, w[kk][1], a0);
        a0 = mfma16(al, w[kk][0], a0);
        a1 = mfma16(ah, w[kk][2], a1);
        a1 = mfma16(ah, w[kk][3], a1);
        a1 = mfma16(al, w[kk][2], a1);
      }
      #pragma unroll
      for (int r = 0; r < 4; r++){
        int row = lg*4 + r;
        int rs = row*256;
        int sw2 = (row & 7) << 4;
        {
          float v = fmaxf(a0[r] + bc0, 0.f);
          u16 hi = f2bu(v); u16 lo = f2bu(v - bu2f(hi));
          int bo = rs + (((colbase + m16)*2) ^ sw2);
          *(u16*)(smem + 24576 + t*8192 + bo) = hi;
          *(u16*)(smem + 24576 + t*8192 + 4096 + bo) = lo;
        }
        {
          float v = fmaxf(a1[r] + bc1, 0.f);
          u16 hi = f2bu(v); u16 lo = f2bu(v - bu2f(hi));
          int bo = rs + (((colbase + 16 + m16)*2) ^ sw2);
          *(u16*)(smem + 24576 + t*8192 + bo) = hi;
          *(u16*)(smem + 24576 + t*8192 + 4096 + bo) = lo;
        }
      }
    }
    LDW(Wm1T_hi, Wm1T_lo, h, w);      // mm2 weights (latency hidden by barrier)
    __syncthreads();                  // all mm1 agg reads + Y writes drained
    if (pf) stage_commit();           // race-safe: no wave reads agg during mm2

    // mm2 over 3 tiles, accumulate P across heads
    #pragma unroll
    for (int t = 0; t < 3; t++){
      #pragma unroll
      for (int kk = 0; kk < 4; kk++){
        bf16x8 yh = *(const bf16x8*)(smem + 24576 + t*8192 + aoff[kk]);
        bf16x8 yl = *(const bf16x8*)(smem + 24576 + t*8192 + 4096 + aoff[kk]);
        P0[t] = mfma16(yh, w[kk][0], P0[t]);
        P0[t] = mfma16(yh, w[kk][1], P0[t]);
        P0[t] = mfma16(yl, w[kk][0], P0[t]);
        P1[t] = mfma16(yh, w[kk][2], P1[t]);
        P1[t] = mfma16(yh, w[kk][3], P1[t]);
        P1[t] = mfma16(yl, w[kk][2], P1[t]);
      }
    }
    __syncthreads();                  // Y reads + agg commit ordered vs next head
  }

  // ---- P -> pS (aliases agg region; drained by loop-final barrier) ----
  #pragma unroll
  for (int t = 0; t < 3; t++){
    #pragma unroll
    for (int r = 0; r < 4; r++){
      int row = t*16 + lg*4 + r;
      pS[row*C_DIM + colbase + m16]      = P0[t][r];
      pS[row*C_DIM + colbase + 16 + m16] = P1[t][r];
    }
  }
  __syncthreads();

  // ---- mlp1: per-wave LN(P + bm1 + proj) + relu -> h1 LDS (12 rows/wave) ----
  for (int g = 0; g < 12; g++){
    int n_l = wv*12 + g;
    int nc = min(nbase + n_l, N_NODES-1);
    int bi = clampi(batch[nc], 0, B_DIM-1);
    float v0 = pS[n_l*C_DIM + lane]      + bm1F[lane]      + proj[bi*C_DIM + lane];
    float v1 = pS[n_l*C_DIM + 64 + lane] + bm1F[64 + lane] + proj[bi*C_DIM + 64 + lane];
    float mean = wave_sum64(v0 + v1) * (1.f/C_DIM);
    float d0 = v0 - mean, d1 = v1 - mean;
    float var = wave_sum64(d0*d0 + d1*d1) * (1.f/C_DIM);
    float rinv = rsqrtf(var + 1e-5f);
    float h0 = fmaxf(d0*rinv*ghF[lane]      + bhF[lane], 0.f);
    float h1v = fmaxf(d1*rinv*ghF[64+lane]  + bhF[64+lane], 0.f);
    int sw3 = (n_l & 7) << 4;
    {
      u16 hi = f2bu(h0); u16 lo = f2bu(h0 - bu2f(hi));
      int bo = n_l*256 + ((lane*2) ^ sw3);
      *(u16*)(smem + 24576 + bo) = hi;
      *(u16*)(smem + 36864 + bo) = lo;
    }
    {
      u16 hi = f2bu(h1v); u16 lo = f2bu(h1v - bu2f(hi));
      int bo = n_l*256 + (((64+lane)*2) ^ sw3);
      *(u16*)(smem + 24576 + bo) = hi;
      *(u16*)(smem + 36864 + bo) = lo;
    }
  }
  LDW(Wm2T_hi, Wm2T_lo, 0, w);        // mlp2 weights (hidden by barrier)
  __syncthreads();

  // ---- mlp2 via MFMA: rows t*16+.. from h1 planes ----
  {
    f32x4 A0[3], A1[3];
    #pragma unroll
    for (int t = 0; t < 3; t++){
      A0[t] = (f32x4){0,0,0,0};
      A1[t] = (f32x4){0,0,0,0};
      #pragma unroll
      for (int kk = 0; kk < 4; kk++){
        bf16x8 yh = *(const bf16x8*)(smem + 24576 + t*4096 + aoff[kk]);
        bf16x8 yl = *(const bf16x8*)(smem + 36864 + t*4096 + aoff[kk]);
        A0[t] = mfma16(yh, w[kk][0], A0[t]);
        A0[t] = mfma16(yh, w[kk][1], A0[t]);
        A0[t] = mfma16(yl, w[kk][0], A0[t]);
        A1[t] = mfma16(yh, w[kk][2], A1[t]);
        A1[t] = mfma16(yh, w[kk][3], A1[t]);
        A1[t] = mfma16(yl, w[kk][2], A1[t]);
      }
    }
    __syncthreads();
    #pragma unroll
    for (int t = 0; t < 3; t++){
      #pragma unroll
      for (int r = 0; r < 4; r++){
        int row = t*16 + lg*4 + r;
        pS[row*C_DIM + colbase + m16]      = A0[t][r];
        pS[row*C_DIM + colbase + 16 + m16] = A1[t][r];
      }
    }
  }
  __syncthreads();

  // ---- residual + final LN (per-wave) -> out ----
  for (int g = 0; g < 12; g++){
    int n_l = wv*12 + g;
    int n = nbase + n_l;
    int nc = min(n, N_NODES-1);
    float x0 = f ? bu2f(x16[(size_t)nc*C_DIM + lane])      : x32[(size_t)nc*C_DIM + lane];
    float x1 = f ? bu2f(x16[(size_t)nc*C_DIM + 64 + lane]) : x32[(size_t)nc*C_DIM + 64 + lane];
    float v0 = pS[n_l*C_DIM + lane]      + bm2F[lane]      + x0;
    float v1 = pS[n_l*C_DIM + 64 + lane] + bm2F[64 + lane] + x1;
    float mean = wave_sum64(v0 + v1) * (1.f/C_DIM);
    float d0 = v0 - mean, d1 = v1 - mean;
    float var = wave_sum64(d0*d0 + d1*d1) * (1.f/C_DIM);
    float rinv = rsqrtf(var + 1e-5f);
    if (lbase + n_l < ncnt){
      stf(out, (size_t)n*C_DIM + lane,      f, d0*rinv*goF[lane]      + boF[lane]);
      stf(out, (size_t)n*C_DIM + 64 + lane, f, d1*rinv*goF[64+lane]   + boF[64+lane]);
    }
  }
}

// ---------------- launcher ----------------

extern "C" void kernel_launch(void* const* d_in, const int* in_sizes, int n_in,
                              void* d_out, int out_size, void* d_ws, size_t ws_size,
                              hipStream_t stream)
{
  const void* x      = d_in[0];
  const void* in1    = d_in[1];
  const void* in2    = d_in[2];
  const int*  batch  = (const int*)d_in[3];
  (void)in_sizes; (void)n_in; (void)out_size;

  char* ws = (char*)d_ws;
  size_t off = 0;
  auto alloc = [&](size_t nbytes)->char*{
    char* p = ws + off;
    off += (nbytes + 255) & ~(size_t)255;
    return p;
  };
  int*   flags = (int*)alloc(8);
  float* arena = (float*)alloc((size_t)ARENA_TOTAL*4);
  int* hist    = (int*)alloc((size_t)N_NODES*4);          // becomes cursor after scan
  int* offsets = (int*)alloc((size_t)(N_NODES+1)*4);
  int* bsums   = (int*)alloc((size_t)SCAN_BLK*4);
  ERec* sortedRec = (ERec*)alloc((size_t)N_EDGES*16);
  float* proj   = (float*)alloc((size_t)B_DIM*C_DIM*4);
  float* xsum   = (float*)alloc((size_t)B_DIM*C_DIM*4);
  int*   counts = (int*)alloc((size_t)B_DIM*4);
  float* tokens = (float*)alloc((size_t)B_DIM*L_DIM*C_DIM*4);  // reused as Bp
  float* x_in   = (float*)alloc((size_t)B_DIM*L_DIM*D_DIM*4);  // reused as dtb
  float* x_c    = (float*)alloc((size_t)B_DIM*L_DIM*D_DIM*4);
  float* Cp     = (float*)alloc((size_t)B_DIM*L_DIM*S_DIM*4);
  float* z_last = (float*)alloc((size_t)B_DIM*D_DIM*4);
  float* y_last = (float*)alloc((size_t)B_DIM*D_DIM*4);
  u16* WcT_hi  = (u16*)alloc((size_t)8*C_DIM*C_DIM*2);
  u16* WcT_lo  = (u16*)alloc((size_t)8*C_DIM*C_DIM*2);
  u16* Wm1T_hi = (u16*)alloc((size_t)8*C_DIM*C_DIM*2);
  u16* Wm1T_lo = (u16*)alloc((size_t)8*C_DIM*C_DIM*2);
  u16* Wm2T_hi = (u16*)alloc((size_t)C_DIM*C_DIM*2);
  u16* Wm2T_lo = (u16*)alloc((size_t)C_DIM*C_DIM*2);

  // dynamic chunking: give all remaining workspace to aggBuf (4 KB/node);
  // chunk is a multiple of 48 so fused tail staging stays in-bounds
  size_t avail = (ws_size > off + 4096) ? (ws_size - off - 4096) : 0;
  long long cn = (long long)(avail / 4096);
  cn -= cn % 48;
  if (cn > MAX_CHUNK) cn = MAX_CHUNK;
  if (cn < 48) cn = 16704;            // fallback (multiple of 48)
  const int chunkN = (int)cn;
  u16* aggBuf = (u16*)alloc((size_t)chunkN * 4096);

  float* Bp  = tokens;
  float* dtb = x_in;

  // weight arena views (match kCum)
  float* WeF   = arena + 0;      float* beF   = arena + 2048;
  float* WcF   = arena + 3072;   float* bcF   = arena + 134144;
  float* WihF  = arena + 135168; float* WhhF  = arena + 184320;
  float* bihF  = arena + 233472; float* bhhF  = arena + 233856;
  float* WinF  = arena + 234240; float* cwF   = arena + 299776;
  float* cbF   = arena + 300800; float* WxF   = arena + 301056;
  float* WdtF  = arena + 368640; float* bdtF  = arena + 370688;
  float* AlF   = arena + 370944; float* DpF   = arena + 403712;
  float* WoutF = arena + 403968; float* gmF   = arena + 436736;
  float* bmF   = arena + 436864; float* Wm1F  = arena + 436992;
  float* bm1F  = arena + 584448; float* ghF   = arena + 584576;
  float* bhF   = arena + 584704; float* Wm2F  = arena + 584832;
  float* bm2F  = arena + 601216; float* goF   = arena + 601344;
  float* boF   = arena + 601472;

  // 0) detect dtype + edge-input order
  detect_kernel<<<1, 64, 0, stream>>>((const unsigned*)d_in[19],
                                      (const unsigned*)in1, (const unsigned*)in2, flags);

  // 1) all weight converts in one launch, then MFMA transpose/split
  Ptrs ptrs;
  for (int i = 0; i < K_SEG; i++) ptrs.p[i] = d_in[4 + i];
  cvt_all_kernel<<<(ARENA_TOTAL + 255)/256, 256, 0, stream>>>(ptrs, arena, flags);
  wtrans_kernel<<<(8*C_DIM*C_DIM + 255)/256, 256, 0, stream>>>(
      WcF, Wm1F, Wm2F, WcT_hi, WcT_lo, Wm1T_hi, Wm1T_lo, Wm2T_hi, Wm2T_lo);

  // 2) counting sort of edges by dst (3-phase parallel scan + pre-gather)
  hipMemsetAsync(hist, 0, (size_t)N_NODES*4, stream);
  hist_kernel<<<(N_EDGES + 255)/256, 256, 0, stream>>>((const int*)in1, (const int*)in2, flags, hist);
  scan1_kernel<<<SCAN_BLK, 1024, 0, stream>>>(hist, offsets, bsums);
  scan2_kernel<<<1, 64, 0, stream>>>(bsums, offsets);
  scan3_kernel<<<SCAN_BLK, 1024, 0, stream>>>(offsets, hist, bsums);
  perm_kernel<<<(N_EDGES + 255)/256, 256, 0, stream>>>(in1, in2, flags, hist, sortedRec);

  // 3) sequential path
  hipMemsetAsync(xsum, 0, (size_t)B_DIM*C_DIM*4 + 256, stream);  // xsum + counts
  pool_kernel<<<(N_NODES + 31)/32, 128, 0, stream>>>(x, batch, xsum, counts, flags);
  gru_kernel<<<B_DIM, 384, 0, stream>>>(xsum, counts, WihF, bihF, WhhF, bhhF, tokens);
  token_proj_kernel<<<B_DIM*L_DIM, 256, 0, stream>>>(tokens, WinF, x_in, z_last);
  xproj_kernel<<<B_DIM*L_DIM, 256, 0, stream>>>(x_in, cwF, cbF, WxF, WdtF, bdtF, dtb, Bp, Cp, x_c);
  ssm_kernel<<<(B_DIM*D_DIM)/4, 256, 0, stream>>>(dtb, Bp, Cp, x_c, AlF, DpF, z_last, y_last);
  xm_kernel<<<B_DIM, 128, 0, stream>>>(y_last, WoutF, gmF, bmF, Wm1F + 8*C_DIM*C_DIM, proj);

  // 4) chunked (ideally 1 chunk): gather -> agg; fused 48-node blocks -> d_out
  for (int n0 = 0; n0 < N_NODES; n0 += chunkN){
    int ncnt = min(chunkN, N_NODES - n0);
    int nsets = (ncnt + NPW - 1) / NPW;
    int nwaves = 2 * nsets;
    gather_kernel<<<(nwaves + 3)/4, 256, 0, stream>>>(
        x, sortedRec, offsets, WeF, beF, flags, aggBuf, n0, ncnt);
    fused_kernel<<<(ncnt + NB - 1)/NB, 256, 0, stream>>>(
        x, aggBuf, n0, ncnt, WcT_hi, WcT_lo, bcF, Wm1T_hi, Wm1T_lo, bm1F,
        proj, batch, ghF, bhF, Wm2T_hi, Wm2T_lo, bm2F, goF, boF, flags, d_out);
  }
}

// Round 17
// 784.367 us; speedup vs baseline: 1.1182x; 1.0299x over previous
//
#include <hip/hip_runtime.h>
#include <hip/hip_bf16.h>

#define N_NODES 50000
#define N_EDGES 640000
#define C_DIM 128
#define B_DIM 64
#define L_DIM 32
#define D_DIM 256
#define S_DIM 128
#define R_DIM 8
#define K_CONV 4
#define NPW 4         // nodes per gather wave
#define NB 64         // nodes per fused block (4 MFMA tiles)
#define MAX_CHUNK 50048
#define SCAN_BLK 49   // ceil(50000/1024)

typedef unsigned short u16;
typedef __attribute__((ext_vector_type(8))) short bf16x8;   // 8 bf16 = 4 VGPRs
typedef __attribute__((ext_vector_type(4))) float f32x4;

struct __align__(16) ERec { int s; float a0, a1; int pad; };

__device__ __forceinline__ float bu2f(u16 u){ return __uint_as_float(((unsigned)u) << 16); }
__device__ __forceinline__ u16 f2bu(float f){
  __hip_bfloat16 h = __float2bfloat16(f);
  return *reinterpret_cast<u16*>(&h);
}
__device__ __forceinline__ float sigmoidf_(float x){ return 1.f/(1.f + expf(-x)); }
__device__ __forceinline__ int clampi(int v, int lo, int hi){ return max(lo, min(v, hi)); }
__device__ __forceinline__ float ldf(const void* p, size_t i, int f){
  return f ? bu2f(((const u16*)p)[i]) : ((const float*)p)[i];
}
__device__ __forceinline__ void stf(void* p, size_t i, int f, float v){
  if (f) ((u16*)p)[i] = f2bu(v); else ((float*)p)[i] = v;
}
__device__ __forceinline__ f32x4 mfma16(bf16x8 a, bf16x8 b, f32x4 c){
  return __builtin_amdgcn_mfma_f32_16x16x32_bf16(a, b, c, 0, 0, 0);
}
__device__ __forceinline__ float wave_sum64(float v){
  #pragma unroll
  for (int off = 32; off; off >>= 1) v += __shfl_xor(v, off);
  return v;
}
// async global->LDS DMA, 16B per lane; queues on vmcnt, no VGPR round trip
__device__ __forceinline__ void gload16(const void* g, void* l){
  __builtin_amdgcn_global_load_lds(
      (const __attribute__((address_space(1))) void*)g,
      (__attribute__((address_space(3))) void*)l, 16, 0, 0);
}

// weight arena layout (element offsets); 27 segments in d_in[4..30] order
constexpr int K_SEG = 27;
constexpr int kCum[K_SEG+1] = {
  0, 2048, 3072, 134144, 135168, 184320, 233472, 233856, 234240, 299776,
  300800, 301056, 368640, 370688, 370944, 403712, 403968, 436736, 436864,
  436992, 584448, 584576, 584704, 584832, 601216, 601344, 601472, 601600 };
#define ARENA_TOTAL 601600

struct Ptrs { const void* p[K_SEG]; };

// ---------------- detection (64-lane parallel) ----------------

__global__ void detect_kernel(const unsigned* dp_bits, const unsigned* cand1,
                              const unsigned* cand2, int* flags){
  int lane = threadIdx.x & 63;
  unsigned idx = (unsigned)((lane * 9973u) % (unsigned)N_EDGES);
  int v1 = (cand1[idx] < (unsigned)N_NODES) ? 1 : 0;
  int v2 = (cand2[idx] < (unsigned)N_NODES) ? 1 : 0;
  unsigned long long m1 = __ballot(v1);
  unsigned long long m2 = __ballot(v2);
  if (lane == 0){
    flags[0] = (dp_bits[0] == 0x3F803F80u) ? 1 : 0;
    flags[1] = (__popcll(m1) > __popcll(m2)) ? 1 : 0;   // 1 => d_in[1] is edge_index
  }
}

// ---------------- fused weight-convert ----------------

__global__ __launch_bounds__(256) void cvt_all_kernel(Ptrs ptrs, float* arena,
                                                      const int* flags){
  int i = blockIdx.x*256 + threadIdx.x;
  if (i >= ARENA_TOTAL) return;
  int lo = 0, hi = K_SEG;
  #pragma unroll
  for (int it = 0; it < 5; it++){
    int mid = (lo + hi) >> 1;
    if (i >= kCum[mid]) lo = mid; else hi = mid;
  }
  int elem = i - kCum[lo];
  const void* sp = ptrs.p[lo];
  arena[i] = flags[0] ? bu2f(((const u16*)sp)[elem]) : ((const float*)sp)[elem];
}

// ---------------- weight transpose + bf16 hi/lo split for MFMA ----------------

__global__ __launch_bounds__(256) void wtrans_kernel(
    const float* __restrict__ WcF, const float* __restrict__ Wm1F,
    const float* __restrict__ Wm2F,
    u16* __restrict__ WcT_hi, u16* __restrict__ WcT_lo,
    u16* __restrict__ Wm1T_hi, u16* __restrict__ Wm1T_lo,
    u16* __restrict__ Wm2T_hi, u16* __restrict__ Wm2T_lo)
{
  int i = blockIdx.x*256 + threadIdx.x;
  if (i >= 8*C_DIM*C_DIM) return;
  int h = i >> 14, j = (i >> 7) & 127, k = i & 127;
  {
    float w = WcF[(h<<14) + (k<<7) + j];
    u16 hi = f2bu(w); u16 lo = f2bu(w - bu2f(hi));
    WcT_hi[i] = hi; WcT_lo[i] = lo;
  }
  {
    float w = Wm1F[((size_t)((h<<7) + k) << 7) + j];
    u16 hi = f2bu(w); u16 lo = f2bu(w - bu2f(hi));
    Wm1T_hi[i] = hi; Wm1T_lo[i] = lo;
  }
  if (i < C_DIM*C_DIM){
    int j2 = i >> 7, k2 = i & 127;
    float w = Wm2F[(k2<<7) + j2];
    u16 hi = f2bu(w); u16 lo = f2bu(w - bu2f(hi));
    Wm2T_hi[i] = hi; Wm2T_lo[i] = lo;
  }
}

// ---------------- counting sort of edges by dst ----------------

__global__ void hist_kernel(const int* __restrict__ eiA, const int* __restrict__ eiB,
                            const int* __restrict__ flags, int* __restrict__ hist){
  const int* dst = (flags[1] ? eiA : eiB) + N_EDGES;
  int e = blockIdx.x*256 + threadIdx.x;
  if (e >= N_EDGES) return;
  int d = clampi(dst[e], 0, N_NODES-1);
  atomicAdd(&hist[d], 1);
}

__global__ __launch_bounds__(1024) void scan1_kernel(const int* __restrict__ hist,
                                                     int* __restrict__ tmp,
                                                     int* __restrict__ bsums){
  __shared__ int buf[1024];
  int b = blockIdx.x, tid = threadIdx.x;
  int i = b*1024 + tid;
  int v = (i < N_NODES) ? hist[i] : 0;
  buf[tid] = v;
  __syncthreads();
  for (int off = 1; off < 1024; off <<= 1){
    int t = (tid >= off) ? buf[tid-off] : 0;
    __syncthreads();
    buf[tid] += t;
    __syncthreads();
  }
  if (i < N_NODES) tmp[i] = buf[tid];       // inclusive
  if (tid == 1023) bsums[b] = buf[1023];
}

__global__ void scan2_kernel(int* __restrict__ bsums, int* __restrict__ offsets){
  if (threadIdx.x == 0){
    int run = 0;
    for (int b = 0; b < SCAN_BLK; b++){ int v = bsums[b]; bsums[b] = run; run += v; }
    offsets[N_NODES] = run;
  }
}

__global__ __launch_bounds__(1024) void scan3_kernel(int* __restrict__ offsets,
                                                     int* __restrict__ hist,
                                                     const int* __restrict__ bsums){
  int b = blockIdx.x, tid = threadIdx.x;
  int i = b*1024 + tid;
  if (i >= N_NODES) return;
  int incl = offsets[i];
  int h = hist[i];
  int excl = incl - h + bsums[b];
  offsets[i] = excl;
  hist[i] = excl;       // cursor copy for perm_kernel
}

__global__ void perm_kernel(const void* __restrict__ in1, const void* __restrict__ in2,
                            const int* __restrict__ flags, int* __restrict__ cursor,
                            ERec* __restrict__ sortedRec){
  int e = blockIdx.x*256 + threadIdx.x;
  if (e >= N_EDGES) return;
  const int f1 = flags[1], f = flags[0];
  const int* ei  = (const int*)(f1 ? in1 : in2);
  const void* eav = f1 ? in2 : in1;
  int d = clampi(ei[N_EDGES + e], 0, N_NODES-1);
  int s = clampi(ei[e], 0, N_NODES-1);
  float a0, a1;
  if (f){ const u16* e16 = (const u16*)eav; a0 = bu2f(e16[2*e]); a1 = bu2f(e16[2*e+1]); }
  else  { const float* e32 = (const float*)eav; a0 = e32[2*e]; a1 = e32[2*e+1]; }
  int pos = atomicAdd(&cursor[d], 1);
  pos = clampi(pos, 0, N_EDGES-1);
  ERec r; r.s = s; r.a0 = a0; r.a1 = a1; r.pad = 0;
  sortedRec[pos] = r;
}

// ---------------- edge gather -> agg (bf16 hi/lo planes) ----------------
// Wave = (chalf, 4-node set). Weights stay in VGPRs across all 4 nodes; each
// wave owns its nodes' channel-half completely -> no LDS, no barriers.
// Edge record packed 16B (one dwordx4 per edge). agg: [nl][h][{hi,lo}][128].

__global__ __launch_bounds__(256, 8) void gather_kernel(
    const void* __restrict__ xv, const ERec* __restrict__ sortedRec,
    const int* __restrict__ offsets,
    const float* __restrict__ WeF, const float* __restrict__ beF,
    const int* __restrict__ flags, u16* __restrict__ aggBuf,
    int n0, int ncnt)
{
  int w = blockIdx.x*4 + (threadIdx.x >> 6);
  int nsets = (ncnt + NPW - 1) / NPW;
  if (w >= 2*nsets) return;
  int chalf = w & 1;
  int nset = w >> 1;
  int lane = threadIdx.x & 63;
  int c = lane + chalf*64;
  const int f = flags[0];
  const u16* x16 = (const u16*)xv; const float* x32 = (const float*)xv;

  float we0[8], we1[8], beh[8];
  #pragma unroll
  for (int h = 0; h < 8; h++){
    we0[h] = WeF[h*2*C_DIM + c];
    we1[h] = WeF[h*2*C_DIM + C_DIM + c];
    beh[h] = beF[h*C_DIM + c];
  }

  auto LD = [&](int q, float& xr, float2& er){
    ERec r = sortedRec[q];          // one 16B load
    er = make_float2(r.a0, r.a1);
    int idx = r.s*C_DIM + c;
    xr = f ? bu2f(x16[idx]) : x32[idx];
  };

  int nl_end = min(nset*NPW + NPW, ncnt);
  for (int nl = nset*NPW; nl < nl_end; nl++){
    int n = n0 + nl;
    int q0 = offsets[n];
    int cnt = offsets[n+1] - q0;

    float acc[8] = {0,0,0,0,0,0,0,0};
    float xA=0.f, xB=0.f, xC=0.f, xD=0.f;
    float2 eA=make_float2(0,0), eB=make_float2(0,0), eC=make_float2(0,0), eD=make_float2(0,0);
    if (cnt > 0) LD(q0+0, xA, eA);
    if (cnt > 1) LD(q0+1, xB, eB);
    if (cnt > 2) LD(q0+2, xC, eC);
    if (cnt > 3) LD(q0+3, xD, eD);

    for (int j = 0; j < cnt; j += 4){
      float ux0=xA, ux1=xB, ux2=xC, ux3=xD;
      float2 ue0=eA, ue1=eB, ue2=eC, ue3=eD;
      if (j+4 < cnt) LD(q0+j+4, xA, eA);
      if (j+5 < cnt) LD(q0+j+5, xB, eB);
      if (j+6 < cnt) LD(q0+j+6, xC, eC);
      if (j+7 < cnt) LD(q0+j+7, xD, eD);
      #pragma unroll
      for (int h = 0; h < 8; h++)
        acc[h] += fmaxf(fmaf(ue0.x, we0[h], fmaf(ue0.y, we1[h], ux0 + beh[h])), 0.f);
      if (j+1 < cnt){
        #pragma unroll
        for (int h = 0; h < 8; h++)
          acc[h] += fmaxf(fmaf(ue1.x, we0[h], fmaf(ue1.y, we1[h], ux1 + beh[h])), 0.f);
      }
      if (j+2 < cnt){
        #pragma unroll
        for (int h = 0; h < 8; h++)
          acc[h] += fmaxf(fmaf(ue2.x, we0[h], fmaf(ue2.y, we1[h], ux2 + beh[h])), 0.f);
      }
      if (j+3 < cnt){
        #pragma unroll
        for (int h = 0; h < 8; h++)
          acc[h] += fmaxf(fmaf(ue3.x, we0[h], fmaf(ue3.y, we1[h], ux3 + beh[h])), 0.f);
      }
    }

    int base = nl*2048 + c;
    #pragma unroll
    for (int h = 0; h < 8; h++){
      u16 hv = f2bu(acc[h]);
      u16 lv = f2bu(acc[h] - bu2f(hv));
      aggBuf[base + h*256]       = hv;
      aggBuf[base + h*256 + 128] = lv;
    }
  }
}

// ---------------- pooling ----------------

__global__ __launch_bounds__(128) void pool_kernel(
    const void* __restrict__ xv, const int* __restrict__ batch,
    float* __restrict__ xsum, int* __restrict__ counts, const int* __restrict__ flags)
{
  int c = threadIdx.x;
  int f = flags[0];
  int n0 = blockIdx.x * 32;
  int nend = min(n0 + 32, N_NODES);
  float acc = 0.f; int cnt = 0;
  int curb = clampi(batch[n0], 0, B_DIM-1);
  for (int n = n0; n < nend; n++){
    int b = clampi(batch[n], 0, B_DIM-1);
    if (b != curb){
      atomicAdd(&xsum[curb*C_DIM + c], acc);
      if (c == 0) atomicAdd(&counts[curb], cnt);
      acc = 0.f; cnt = 0; curb = b;
    }
    acc += ldf(xv, (size_t)n*C_DIM + c, f);
    cnt++;
  }
  atomicAdd(&xsum[curb*C_DIM + c], acc);
  if (c == 0) atomicAdd(&counts[curb], cnt);
}

// ---------------- GRU (Whh column register-cached) ----------------

__global__ __launch_bounds__(384, 1) void gru_kernel(
    const float* __restrict__ xsum, const int* __restrict__ counts,
    const float* __restrict__ Wih, const float* __restrict__ bih,
    const float* __restrict__ Whh, const float* __restrict__ bhh,
    float* __restrict__ tokens)
{
  int b = blockIdx.x, j = threadIdx.x;
  __shared__ float xm[C_DIM], h[C_DIM], gh[3*C_DIM], sgi[3*C_DIM];
  __shared__ float mxS;
  if (j == 0){
    int m = 1;
    for (int bb = 0; bb < B_DIM; bb++) m = max(m, counts[bb]);
    mxS = (float)m;
  }
  __syncthreads();
  if (j < C_DIM){ xm[j] = xsum[b*C_DIM + j] / mxS; h[j] = 0.f; }
  __syncthreads();

  {
    float a0=0.f, a1=0.f, a2=0.f, a3=0.f;
    for (int k = 0; k < C_DIM; k += 4){
      a0 = fmaf(xm[k],   Wih[(k  )*384 + j], a0);
      a1 = fmaf(xm[k+1], Wih[(k+1)*384 + j], a1);
      a2 = fmaf(xm[k+2], Wih[(k+2)*384 + j], a2);
      a3 = fmaf(xm[k+3], Wih[(k+3)*384 + j], a3);
    }
    sgi[j] = bih[j] + ((a0 + a1) + (a2 + a3));
  }

  float w[C_DIM];
  #pragma unroll
  for (int k = 0; k < C_DIM; k++) w[k] = Whh[k*384 + j];
  float bh = bhh[j];
  __syncthreads();

  float g_ir = 0.f, g_iz = 0.f, g_in = 0.f;
  if (j < C_DIM){ g_ir = sgi[j]; g_iz = sgi[C_DIM + j]; g_in = sgi[2*C_DIM + j]; }

  for (int t = 0; t < L_DIM; t++){
    float a0=0.f, a1=0.f, a2=0.f, a3=0.f;
    #pragma unroll
    for (int k = 0; k < C_DIM; k += 4){
      a0 = fmaf(h[k],   w[k],   a0);
      a1 = fmaf(h[k+1], w[k+1], a1);
      a2 = fmaf(h[k+2], w[k+2], a2);
      a3 = fmaf(h[k+3], w[k+3], a3);
    }
    gh[j] = bh + ((a0 + a1) + (a2 + a3));
    __syncthreads();
    if (j < C_DIM){
      float r  = sigmoidf_(g_ir + gh[j]);
      float z  = sigmoidf_(g_iz + gh[C_DIM + j]);
      float nn = tanhf(g_in + r*gh[2*C_DIM + j]);
      float hn = (1.f - z)*nn + z*h[j];
      h[j] = hn;
      tokens[((size_t)b*L_DIM + t)*C_DIM + j] = hn;
    }
    __syncthreads();
  }
}

// ---------------- token projection (Win) ----------------

__global__ __launch_bounds__(256) void token_proj_kernel(
    const float* __restrict__ tokens, const float* __restrict__ Win,
    float* __restrict__ x_in, float* __restrict__ z_last)
{
  int row = blockIdx.x;
  int d = threadIdx.x;
  __shared__ float tok[C_DIM];
  if (d < C_DIM) tok[d] = tokens[(size_t)row*C_DIM + d];
  __syncthreads();
  float acc = 0.f;
  for (int k = 0; k < C_DIM; k++) acc = fmaf(tok[k], Win[k*512 + d], acc);
  x_in[(size_t)row*D_DIM + d] = acc;
  if ((row & (L_DIM-1)) == L_DIM-1){
    float acc2 = 0.f;
    for (int k = 0; k < C_DIM; k++) acc2 = fmaf(tok[k], Win[k*512 + D_DIM + d], acc2);
    z_last[(row >> 5)*D_DIM + d] = acc2;
  }
}

// ---------------- xproj ----------------

__global__ __launch_bounds__(256) void xproj_kernel(
    const float* __restrict__ x_in, const float* __restrict__ cw,
    const float* __restrict__ cb, const float* __restrict__ Wx,
    const float* __restrict__ Wdt, const float* __restrict__ bdt,
    float* __restrict__ dt, float* __restrict__ Bp, float* __restrict__ Cp,
    float* __restrict__ x_c)
{
  int row = blockIdx.x; int tid = threadIdx.x;
  int t = row & (L_DIM-1);
  __shared__ float xr[D_DIM];
  __shared__ float dtr[R_DIM];
  float acc0 = cb[tid];
  #pragma unroll
  for (int k = 0; k < K_CONV; k++){
    int tt = t + k - (K_CONV-1);
    if (tt >= 0) acc0 = fmaf(cw[tid*K_CONV + k], x_in[(size_t)(row + tt - t)*D_DIM + tid], acc0);
  }
  float xcv = acc0 * sigmoidf_(acc0);
  x_c[(size_t)row*D_DIM + tid] = xcv;
  xr[tid] = xcv;
  __syncthreads();
  float acc = 0.f;
  #pragma unroll 4
  for (int k = 0; k < D_DIM; k++) acc = fmaf(xr[k], Wx[k*264 + tid], acc);
  if (tid < R_DIM)              dtr[tid] = acc;
  else if (tid < R_DIM+S_DIM)   Bp[(size_t)row*S_DIM + tid - R_DIM] = acc;
  else                          Cp[(size_t)row*S_DIM + tid - (R_DIM+S_DIM)] = acc;
  if (tid < 264 - D_DIM){
    float acc2 = 0.f;
    #pragma unroll 4
    for (int k = 0; k < D_DIM; k++) acc2 = fmaf(xr[k], Wx[k*264 + D_DIM + tid], acc2);
    Cp[(size_t)row*S_DIM + (D_DIM - (R_DIM+S_DIM)) + tid] = acc2;
  }
  __syncthreads();
  float a = bdt[tid];
  #pragma unroll
  for (int r = 0; r < R_DIM; r++) a = fmaf(dtr[r], Wdt[r*D_DIM + tid], a);
  dt[(size_t)row*D_DIM + tid] = (a > 20.f) ? a : log1pf(expf(a));
}

// ---------------- SSM scan ----------------

__global__ __launch_bounds__(256) void ssm_kernel(
    const float* __restrict__ dt, const float* __restrict__ Bp,
    const float* __restrict__ Cp, const float* __restrict__ x_c,
    const float* __restrict__ A_log, const float* __restrict__ Dp_,
    const float* __restrict__ z_last, float* __restrict__ y_last)
{
  int wid = (blockIdx.x*256 + threadIdx.x) >> 6;
  int lane = threadIdx.x & 63;
  int b = wid >> 8, d = wid & (D_DIM-1);
  int s0 = lane*2;
  float A0 = -expf(A_log[d*S_DIM + s0]);
  float A1 = -expf(A_log[d*S_DIM + s0 + 1]);
  float h0 = 0.f, h1 = 0.f;
  for (int t = 0; t < L_DIM; t++){
    int row = b*L_DIM + t;
    float dtv = dt[(size_t)row*D_DIM + d];
    float xv  = x_c[(size_t)row*D_DIM + d];
    float bx = dtv * xv;
    float2 Bv = ((const float2*)(Bp + (size_t)row*S_DIM))[lane];
    h0 = fmaf(expf(dtv*A0), h0, bx*Bv.x);
    h1 = fmaf(expf(dtv*A1), h1, bx*Bv.y);
  }
  int row = b*L_DIM + (L_DIM-1);
  float2 Cv = ((const float2*)(Cp + (size_t)row*S_DIM))[lane];
  float y = h0*Cv.x + h1*Cv.y;
  #pragma unroll
  for (int off = 32; off; off >>= 1) y += __shfl_down(y, off);
  if (lane == 0){
    float xc = x_c[(size_t)row*D_DIM + d];
    float yv = y + Dp_[d]*xc;
    float z  = z_last[b*D_DIM + d];
    yv *= z * sigmoidf_(z);
    y_last[b*D_DIM + d] = yv;
  }
}

// ---------------- proj = ln(y_last @ Wout) @ Wm1[8C:] ----------------

__device__ __forceinline__ float block_sum_128(float v, float* red){
  int c = threadIdx.x;
  red[c] = v; __syncthreads();
  if (c < 64) red[c] += red[c+64];
  __syncthreads();
  if (c < 64){
    float r = red[c];
    #pragma unroll
    for (int off = 32; off; off >>= 1) r += __shfl_down(r, off);
    if (c == 0) red[0] = r;
  }
  __syncthreads();
  float out = red[0];
  __syncthreads();
  return out;
}

__global__ __launch_bounds__(128) void xm_kernel(
    const float* __restrict__ y_last, const float* __restrict__ Wout,
    const float* __restrict__ g_m, const float* __restrict__ b_m,
    const float* __restrict__ Wm1x, float* __restrict__ proj)
{
  int b = blockIdx.x, c = threadIdx.x;
  __shared__ float yr[D_DIM];
  __shared__ float red[C_DIM];
  __shared__ float xmr[C_DIM];
  yr[c]        = y_last[b*D_DIM + c];
  yr[C_DIM+c]  = y_last[b*D_DIM + C_DIM + c];
  __syncthreads();
  float acc = 0.f;
  for (int k = 0; k < D_DIM; k++) acc = fmaf(yr[k], Wout[k*C_DIM + c], acc);
  float mean = block_sum_128(acc, red) * (1.f/C_DIM);
  float dv = acc - mean;
  float var = block_sum_128(dv*dv, red) * (1.f/C_DIM);
  float mo = dv*rsqrtf(var + 1e-5f)*g_m[c] + b_m[c];
  xmr[c] = mo;
  __syncthreads();
  float p = 0.f;
  for (int k = 0; k < C_DIM; k++) p = fmaf(xmr[k], Wm1x[k*C_DIM + c], p);
  proj[b*C_DIM + c] = p;
}

// ---------------- fused_kernel: 64 nodes/block, async DMA agg staging ----------------
// Per head: w1 LDW; mm1 (4 tiles) from LDS agg -> Y; w2 LDW; BARRIER; issue 8
// global_load_lds DMA ops for head h+1's agg (race-free: agg readers drained,
// mm2 reads Y only; zero VGPR cost, queue on vmcnt); mm2 accumulating P in
// regs; BARRIER (vmcnt drained -> agg[h+1] visible). LDS agg is LINEAR with
// pre-swizzled global source (T21): src unit u^(g&7); swizzled ahoff reads
// cancel the XOR.

__global__ __launch_bounds__(256, 2) void fused_kernel(
    const void* __restrict__ xv, const u16* __restrict__ aggBuf, int n0, int ncnt,
    const u16* __restrict__ WcT_hi, const u16* __restrict__ WcT_lo,
    const float* __restrict__ bcF,
    const u16* __restrict__ Wm1T_hi, const u16* __restrict__ Wm1T_lo,
    const float* __restrict__ bm1F, const float* __restrict__ proj,
    const int* __restrict__ batch,
    const float* __restrict__ ghF, const float* __restrict__ bhF,
    const u16* __restrict__ Wm2T_hi, const u16* __restrict__ Wm2T_lo,
    const float* __restrict__ bm2F,
    const float* __restrict__ goF, const float* __restrict__ boF,
    const int* __restrict__ flags, void* __restrict__ out)
{
  // LDS: [0,32768) agg [4 tiles][16 nodes][512B] (linear; source pre-swizzled)
  //      (aliased as pS f32[64][128] after head loop)
  //      [32768,65536) Y: per tile t at 32768+t*8192 (hi 4KB | lo 4KB)
  //                    LN phase: h1_hi [64][256B] at 32768, h1_lo at 49152
  __shared__ __align__(16) char smem[65536];
  float* pS = (float*)smem;

  const int tid = threadIdx.x;
  const int f = flags[0];
  const u16* x16 = (const u16*)xv; const float* x32 = (const float*)xv;
  const int lbase = blockIdx.x * NB;
  const int nbase = n0 + lbase;

  const int lane = tid & 63;
  const int wv = tid >> 6;
  const int m16 = lane & 15;
  const int lg = lane >> 4;
  const int colbase = wv * 32;
  const int jA = colbase + m16;

  int ahoff[4], aoff[4];
  #pragma unroll
  for (int kk = 0; kk < 4; kk++){
    int sw = (m16 & 7) << 4;
    ahoff[kk] = m16*512 + ((kk*64 + lg*16) ^ sw);
    aoff[kk]  = m16*256 + ((kk*64 + lg*16) ^ sw);
  }

  // DMA staging map: 2048 16B-units; 8 per thread. Unit p = tid + j*256:
  //   t=p>>9, g=(p>>5)&15, u=p&31; node = lbase+t*16+g.
  //   LDS dst linear = p*16 (per wave: base + lane*16, matches DMA semantics).
  //   Global src pre-swizzled: byte ((node*8+h)<<9) + ((u^(g&7))<<4).
  unsigned sg_off[8];   // h=0 source byte offsets; per head add h<<9
  int sg_dst[8];
  #pragma unroll
  for (int j = 0; j < 8; j++){
    int p = tid + j*256;
    int t = p >> 9, g = (p >> 5) & 15, u = p & 31;
    int node = lbase + t*16 + g;
    sg_off[j] = ((unsigned)(node*8) << 9) + (unsigned)((u ^ (g & 7)) << 4);
    sg_dst[j] = p << 4;
  }
  auto stage_dma = [&](int h){
    #pragma unroll
    for (int j = 0; j < 8; j++)
      gload16((const char*)aggBuf + sg_off[j] + (h << 9), smem + sg_dst[j]);
  };
  auto LDW = [&](const u16* Whi, const u16* Wlo, int h, bf16x8 (*w)[4]){
    #pragma unroll
    for (int kk = 0; kk < 4; kk++){
      size_t bi0 = ((size_t)(h*C_DIM + jA) << 7) + kk*32 + lg*8;
      w[kk][0] = *(const bf16x8*)(Whi + bi0);
      w[kk][1] = *(const bf16x8*)(Wlo + bi0);
      w[kk][2] = *(const bf16x8*)(Whi + bi0 + 2048);
      w[kk][3] = *(const bf16x8*)(Wlo + bi0 + 2048);
    }
  };

  // prologue: DMA head 0's agg; barrier drains vmcnt
  stage_dma(0);
  __syncthreads();

  f32x4 P0[4], P1[4];
  #pragma unroll
  for (int t = 0; t < 4; t++){
    P0[t] = (f32x4){0,0,0,0};
    P1[t] = (f32x4){0,0,0,0};
  }

  bf16x8 w[4][4];
  for (int h = 0; h < 8; h++){
    const bool pf = (h+1 < 8);
    LDW(WcT_hi, WcT_lo, h, w);        // mm1 weights
    float bc0 = bcF[h*C_DIM + colbase + m16];
    float bc1 = bcF[h*C_DIM + colbase + 16 + m16];

    // mm1 over 4 tiles -> Y
    #pragma unroll
    for (int t = 0; t < 4; t++){
      f32x4 a0 = {0,0,0,0}, a1 = {0,0,0,0};
      #pragma unroll
      for (int kk = 0; kk < 4; kk++){
        bf16x8 ah = *(const bf16x8*)(smem + t*8192 + ahoff[kk]);
        bf16x8 al = *(const bf16x8*)(smem + t*8192 + ahoff[kk] + 256);
        a0 = mfma16(ah, w[kk][0], a0);
        a0 = mfma16(ah, w[kk][1], a0);
        a0 = mfma16(al, w[kk][0], a0);
        a1 = mfma16(ah, w[kk][2], a1);
        a1 = mfma16(ah, w[kk][3], a1);
        a1 = mfma16(al, w[kk][2], a1);
      }
      #pragma unroll
      for (int r = 0; r < 4; r++){
        int row = lg*4 + r;
        int rs = row*256;
        int sw2 = (row & 7) << 4;
        {
          float v = fmaxf(a0[r] + bc0, 0.f);
          u16 hi = f2bu(v); u16 lo = f2bu(v - bu2f(hi));
          int bo = rs + (((colbase + m16)*2) ^ sw2);
          *(u16*)(smem + 32768 + t*8192 + bo) = hi;
          *(u16*)(smem + 32768 + t*8192 + 4096 + bo) = lo;
        }
        {
          float v = fmaxf(a1[r] + bc1, 0.f);
          u16 hi = f2bu(v); u16 lo = f2bu(v - bu2f(hi));
          int bo = rs + (((colbase + 16 + m16)*2) ^ sw2);
          *(u16*)(smem + 32768 + t*8192 + bo) = hi;
          *(u16*)(smem + 32768 + t*8192 + 4096 + bo) = lo;
        }
      }
    }
    LDW(Wm1T_hi, Wm1T_lo, h, w);      // mm2 weights
    __syncthreads();                  // all mm1 agg reads + Y writes drained
    if (pf) stage_dma(h+1);           // async DMA next head's agg (flies under mm2)

    // mm2 over 4 tiles, accumulate P across heads
    #pragma unroll
    for (int t = 0; t < 4; t++){
      #pragma unroll
      for (int kk = 0; kk < 4; kk++){
        bf16x8 yh = *(const bf16x8*)(smem + 32768 + t*8192 + aoff[kk]);
        bf16x8 yl = *(const bf16x8*)(smem + 32768 + t*8192 + 4096 + aoff[kk]);
        P0[t] = mfma16(yh, w[kk][0], P0[t]);
        P0[t] = mfma16(yh, w[kk][1], P0[t]);
        P0[t] = mfma16(yl, w[kk][0], P0[t]);
        P1[t] = mfma16(yh, w[kk][2], P1[t]);
        P1[t] = mfma16(yh, w[kk][3], P1[t]);
        P1[t] = mfma16(yl, w[kk][2], P1[t]);
      }
    }
    __syncthreads();                  // drains vmcnt -> agg[h+1] visible
  }

  // ---- P -> pS (aliases agg region; drained by loop-final barrier) ----
  #pragma unroll
  for (int t = 0; t < 4; t++){
    #pragma unroll
    for (int r = 0; r < 4; r++){
      int row = t*16 + lg*4 + r;
      pS[row*C_DIM + colbase + m16]      = P0[t][r];
      pS[row*C_DIM + colbase + 16 + m16] = P1[t][r];
    }
  }
  __syncthreads();

  // ---- mlp1: per-wave LN(P + bm1 + proj) + relu -> h1 LDS ----
  for (int g = 0; g < 16; g++){
    int n_l = wv*16 + g;
    int nc = min(nbase + n_l, N_NODES-1);
    int bi = clampi(batch[nc], 0, B_DIM-1);
    float v0 = pS[n_l*C_DIM + lane]      + bm1F[lane]      + proj[bi*C_DIM + lane];
    float v1 = pS[n_l*C_DIM + 64 + lane] + bm1F[64 + lane] + proj[bi*C_DIM + 64 + lane];
    float mean = wave_sum64(v0 + v1) * (1.f/C_DIM);
    float d0 = v0 - mean, d1 = v1 - mean;
    float var = wave_sum64(d0*d0 + d1*d1) * (1.f/C_DIM);
    float rinv = rsqrtf(var + 1e-5f);
    float h0 = fmaxf(d0*rinv*ghF[lane]      + bhF[lane], 0.f);
    float h1v = fmaxf(d1*rinv*ghF[64+lane]  + bhF[64+lane], 0.f);
    int sw3 = (n_l & 7) << 4;
    {
      u16 hi = f2bu(h0); u16 lo = f2bu(h0 - bu2f(hi));
      int bo = n_l*256 + ((lane*2) ^ sw3);
      *(u16*)(smem + 32768 + bo) = hi;
      *(u16*)(smem + 49152 + bo) = lo;
    }
    {
      u16 hi = f2bu(h1v); u16 lo = f2bu(h1v - bu2f(hi));
      int bo = n_l*256 + (((64+lane)*2) ^ sw3);
      *(u16*)(smem + 32768 + bo) = hi;
      *(u16*)(smem + 49152 + bo) = lo;
    }
  }
  bf16x8 w2[4][4];
  LDW(Wm2T_hi, Wm2T_lo, 0, w2);       // mlp2 weights (hidden by barrier)
  __syncthreads();

  // ---- mlp2 via MFMA: rows t*16+.. from h1 planes ----
  {
    f32x4 A0[4], A1[4];
    #pragma unroll
    for (int t = 0; t < 4; t++){
      A0[t] = (f32x4){0,0,0,0};
      A1[t] = (f32x4){0,0,0,0};
      #pragma unroll
      for (int kk = 0; kk < 4; kk++){
        bf16x8 yh = *(const bf16x8*)(smem + 32768 + t*4096 + aoff[kk]);
        bf16x8 yl = *(const bf16x8*)(smem + 49152 + t*4096 + aoff[kk]);
        A0[t] = mfma16(yh, w2[kk][0], A0[t]);
        A0[t] = mfma16(yh, w2[kk][1], A0[t]);
        A0[t] = mfma16(yl, w2[kk][0], A0[t]);
        A1[t] = mfma16(yh, w2[kk][2], A1[t]);
        A1[t] = mfma16(yh, w2[kk][3], A1[t]);
        A1[t] = mfma16(yl, w2[kk][2], A1[t]);
      }
    }
    __syncthreads();
    #pragma unroll
    for (int t = 0; t < 4; t++){
      #pragma unroll
      for (int r = 0; r < 4; r++){
        int row = t*16 + lg*4 + r;
        pS[row*C_DIM + colbase + m16]      = A0[t][r];
        pS[row*C_DIM + colbase + 16 + m16] = A1[t][r];
      }
    }
  }
  __syncthreads();

  // ---- residual + final LN (per-wave) -> out ----
  for (int g = 0; g < 16; g++){
    int n_l = wv*16 + g;
    int n = nbase + n_l;
    int nc = min(n, N_NODES-1);
    float x0 = f ? bu2f(x16[(size_t)nc*C_DIM + lane])      : x32[(size_t)nc*C_DIM + lane];
    float x1 = f ? bu2f(x16[(size_t)nc*C_DIM + 64 + lane]) : x32[(size_t)nc*C_DIM + 64 + lane];
    float v0 = pS[n_l*C_DIM + lane]      + bm2F[lane]      + x0;
    float v1 = pS[n_l*C_DIM + 64 + lane] + bm2F[64 + lane] + x1;
    float mean = wave_sum64(v0 + v1) * (1.f/C_DIM);
    float d0 = v0 - mean, d1 = v1 - mean;
    float var = wave_sum64(d0*d0 + d1*d1) * (1.f/C_DIM);
    float rinv = rsqrtf(var + 1e-5f);
    if (lbase + n_l < ncnt){
      stf(out, (size_t)n*C_DIM + lane,      f, d0*rinv*goF[lane]      + boF[lane]);
      stf(out, (size_t)n*C_DIM + 64 + lane, f, d1*rinv*goF[64+lane]   + boF[64+lane]);
    }
  }
}

// ---------------- launcher ----------------

extern "C" void kernel_launch(void* const* d_in, const int* in_sizes, int n_in,
                              void* d_out, int out_size, void* d_ws, size_t ws_size,
                              hipStream_t stream)
{
  const void* x      = d_in[0];
  const void* in1    = d_in[1];
  const void* in2    = d_in[2];
  const int*  batch  = (const int*)d_in[3];
  (void)in_sizes; (void)n_in; (void)out_size;

  char* ws = (char*)d_ws;
  size_t off = 0;
  auto alloc = [&](size_t nbytes)->char*{
    char* p = ws + off;
    off += (nbytes + 255) & ~(size_t)255;
    return p;
  };
  int*   flags = (int*)alloc(8);
  float* arena = (float*)alloc((size_t)ARENA_TOTAL*4);
  int* hist    = (int*)alloc((size_t)N_NODES*4);          // becomes cursor after scan
  int* offsets = (int*)alloc((size_t)(N_NODES+1)*4);
  int* bsums   = (int*)alloc((size_t)SCAN_BLK*4);
  ERec* sortedRec = (ERec*)alloc((size_t)N_EDGES*16);
  float* proj   = (float*)alloc((size_t)B_DIM*C_DIM*4);
  float* xsum   = (float*)alloc((size_t)B_DIM*C_DIM*4);
  int*   counts = (int*)alloc((size_t)B_DIM*4);
  float* tokens = (float*)alloc((size_t)B_DIM*L_DIM*C_DIM*4);  // reused as Bp
  float* x_in   = (float*)alloc((size_t)B_DIM*L_DIM*D_DIM*4);  // reused as dtb
  float* x_c    = (float*)alloc((size_t)B_DIM*L_DIM*D_DIM*4);
  float* Cp     = (float*)alloc((size_t)B_DIM*L_DIM*S_DIM*4);
  float* z_last = (float*)alloc((size_t)B_DIM*D_DIM*4);
  float* y_last = (float*)alloc((size_t)B_DIM*D_DIM*4);
  u16* WcT_hi  = (u16*)alloc((size_t)8*C_DIM*C_DIM*2);
  u16* WcT_lo  = (u16*)alloc((size_t)8*C_DIM*C_DIM*2);
  u16* Wm1T_hi = (u16*)alloc((size_t)8*C_DIM*C_DIM*2);
  u16* Wm1T_lo = (u16*)alloc((size_t)8*C_DIM*C_DIM*2);
  u16* Wm2T_hi = (u16*)alloc((size_t)C_DIM*C_DIM*2);
  u16* Wm2T_lo = (u16*)alloc((size_t)C_DIM*C_DIM*2);

  // dynamic chunking: give all remaining workspace to aggBuf (4 KB/node)
  size_t avail = (ws_size > off + 4096) ? (ws_size - off - 4096) : 0;
  long long cn = (long long)(avail / 4096);
  cn &= ~63LL;
  if (cn > MAX_CHUNK) cn = MAX_CHUNK;
  if (cn < 64) cn = 16704;            // fallback
  const int chunkN = (int)cn;
  u16* aggBuf = (u16*)alloc((size_t)chunkN * 4096);

  float* Bp  = tokens;
  float* dtb = x_in;

  // weight arena views (match kCum)
  float* WeF   = arena + 0;      float* beF   = arena + 2048;
  float* WcF   = arena + 3072;   float* bcF   = arena + 134144;
  float* WihF  = arena + 135168; float* WhhF  = arena + 184320;
  float* bihF  = arena + 233472; float* bhhF  = arena + 233856;
  float* WinF  = arena + 234240; float* cwF   = arena + 299776;
  float* cbF   = arena + 300800; float* WxF   = arena + 301056;
  float* WdtF  = arena + 368640; float* bdtF  = arena + 370688;
  float* AlF   = arena + 370944; float* DpF   = arena + 403712;
  float* WoutF = arena + 403968; float* gmF   = arena + 436736;
  float* bmF   = arena + 436864; float* Wm1F  = arena + 436992;
  float* bm1F  = arena + 584448; float* ghF   = arena + 584576;
  float* bhF   = arena + 584704; float* Wm2F  = arena + 584832;
  float* bm2F  = arena + 601216; float* goF   = arena + 601344;
  float* boF   = arena + 601472;

  // 0) detect dtype + edge-input order
  detect_kernel<<<1, 64, 0, stream>>>((const unsigned*)d_in[19],
                                      (const unsigned*)in1, (const unsigned*)in2, flags);

  // 1) all weight converts in one launch, then MFMA transpose/split
  Ptrs ptrs;
  for (int i = 0; i < K_SEG; i++) ptrs.p[i] = d_in[4 + i];
  cvt_all_kernel<<<(ARENA_TOTAL + 255)/256, 256, 0, stream>>>(ptrs, arena, flags);
  wtrans_kernel<<<(8*C_DIM*C_DIM + 255)/256, 256, 0, stream>>>(
      WcF, Wm1F, Wm2F, WcT_hi, WcT_lo, Wm1T_hi, Wm1T_lo, Wm2T_hi, Wm2T_lo);

  // 2) counting sort of edges by dst (3-phase parallel scan + pre-gather)
  hipMemsetAsync(hist, 0, (size_t)N_NODES*4, stream);
  hist_kernel<<<(N_EDGES + 255)/256, 256, 0, stream>>>((const int*)in1, (const int*)in2, flags, hist);
  scan1_kernel<<<SCAN_BLK, 1024, 0, stream>>>(hist, offsets, bsums);
  scan2_kernel<<<1, 64, 0, stream>>>(bsums, offsets);
  scan3_kernel<<<SCAN_BLK, 1024, 0, stream>>>(offsets, hist, bsums);
  perm_kernel<<<(N_EDGES + 255)/256, 256, 0, stream>>>(in1, in2, flags, hist, sortedRec);

  // 3) sequential path
  hipMemsetAsync(xsum, 0, (size_t)B_DIM*C_DIM*4 + 256, stream);  // xsum + counts
  pool_kernel<<<(N_NODES + 31)/32, 128, 0, stream>>>(x, batch, xsum, counts, flags);
  gru_kernel<<<B_DIM, 384, 0, stream>>>(xsum, counts, WihF, bihF, WhhF, bhhF, tokens);
  token_proj_kernel<<<B_DIM*L_DIM, 256, 0, stream>>>(tokens, WinF, x_in, z_last);
  xproj_kernel<<<B_DIM*L_DIM, 256, 0, stream>>>(x_in, cwF, cbF, WxF, WdtF, bdtF, dtb, Bp, Cp, x_c);
  ssm_kernel<<<(B_DIM*D_DIM)/4, 256, 0, stream>>>(dtb, Bp, Cp, x_c, AlF, DpF, z_last, y_last);
  xm_kernel<<<B_DIM, 128, 0, stream>>>(y_last, WoutF, gmF, bmF, Wm1F + 8*C_DIM*C_DIM, proj);

  // 4) chunked (ideally 1 chunk): gather -> agg; fused (DMA staging) -> d_out
  for (int n0 = 0; n0 < N_NODES; n0 += chunkN){
    int ncnt = min(chunkN, N_NODES - n0);
    int nsets = (ncnt + NPW - 1) / NPW;
    int nwaves = 2 * nsets;
    gather_kernel<<<(nwaves + 3)/4, 256, 0, stream>>>(
        x, sortedRec, offsets, WeF, beF, flags, aggBuf, n0, ncnt);
    fused_kernel<<<(ncnt + NB - 1)/NB, 256, 0, stream>>>(
        x, aggBuf, n0, ncnt, WcT_hi, WcT_lo, bcF, Wm1T_hi, Wm1T_lo, bm1F,
        proj, batch, ghF, bhF, Wm2T_hi, Wm2T_lo, bm2F, goF, boF, flags, d_out);
  }
}